// Round 8
// baseline (257.576 us; speedup 1.0000x reference)
//
#include <hip/hip_runtime.h>
#include <math.h>

#define H_   768
#define NH_  4
#define HD_  192
#define E_   9
#define R_   12
#define D_   64
#define B_   4
#define S_   1024
#define H3_  (3 * H_)
#define MBS_ (B_ * S_)

typedef unsigned short u16;
typedef __attribute__((ext_vector_type(4))) int   i32x4;
typedef __attribute__((ext_vector_type(4))) float f32x4;

static const long OUT_REL_OFF = (long)B_ * E_ * S_ * S_;                    // 37,748,736
static const long OUT_ENH_OFF = OUT_REL_OFF + (long)B_ * R_ * S_ * S_;      // 88,080,384

__device__ __forceinline__ u16 f2bf(float f) {
    unsigned u = __builtin_bit_cast(unsigned, f);
    return (u16)((u + 0x7fffu + ((u >> 16) & 1u)) >> 16);
}
__device__ __forceinline__ float bf2f(u16 h) {
    return __builtin_bit_cast(float, (unsigned)h << 16);
}
__device__ __forceinline__ void gload16(const u16* g, u16* l) {
    __builtin_amdgcn_global_load_lds(
        (__attribute__((address_space(1))) void*)g,
        (__attribute__((address_space(3))) void*)l, 16, 0, 0);
}
__device__ __forceinline__ void mfma_bf16(f32x4& acc, i32x4 a, i32x4 b) {
    asm volatile("v_mfma_f32_16x16x32_bf16 %0, %1, %2, %0"
                 : "+v"(acc) : "v"(a), "v"(b));
}

// ---------------------------------------------------------------------------
// bf16 MFMA GEMM, NT (same as round 7; EPI 5/6 retired — attention is fused).
// ---------------------------------------------------------------------------
template<int BM, int BN, int EPI, int OBF, int PIPE>
__global__ __launch_bounds__(256) void gemm_mfma(
    const u16* __restrict__ A, const u16* __restrict__ Bw,
    const float* __restrict__ bias, void* __restrict__ Cv,
    int K, int lda, int ldb, int ldc, int nh,
    long sAb, long sAh, long sBb, long sBh, long sCb, long sCh,
    const float* __restrict__ mask, float scale, float* __restrict__ aux)
{
    constexpr int MI = BM / 32, NJ = BN / 32;
    constexpr int BUFE = (BM + BN) * 64;
    constexpr int LPS  = BM / 32 + BN / 32;
    const int z = blockIdx.z;
    const int zb = z / nh, zh = z - zb * nh;
    A  += zb * sAb + zh * sAh;
    Bw += zb * sBb + zh * sBh;

    const int gx = gridDim.x, gy = gridDim.y;
    int id = blockIdx.y * gx + blockIdx.x;
    const int nwg = gx * gy;
    if ((nwg & 7) == 0) id = (id & 7) * (nwg >> 3) + (id >> 3);
    const int bx = id % gx, by = id / gx;
    const int m0 = by * BM, n0 = bx * BN;

    __shared__ u16 lds[(PIPE ? 2 : 1) * BUFE];

    const int t = threadIdx.x;
    const int lane = t & 63, wid = t >> 6;
    const int wr = wid >> 1, wc = wid & 1;
    const int l16 = lane & 15, l4 = lane >> 4;

    auto stage = [&](int kt, u16* la) {
        u16* lb = la + BM * 64;
        const int k0 = kt << 6;
        #pragma unroll
        for (int i = 0; i < BM / 32; ++i) {
            const int e = i * 256 + t;
            const int row = e >> 3;
            const int c = ((e & 7) ^ (row & 7)) << 3;
            gload16(A + (long)(m0 + row) * lda + k0 + c, la + e * 8);
        }
        #pragma unroll
        for (int i = 0; i < BN / 32; ++i) {
            const int e = i * 256 + t;
            const int row = e >> 3;
            const int c = ((e & 7) ^ (row & 7)) << 3;
            gload16(Bw + (long)(n0 + row) * ldb + k0 + c, lb + e * 8);
        }
    };

    f32x4 acc[MI][NJ];
    #pragma unroll
    for (int mi = 0; mi < MI; ++mi)
        #pragma unroll
        for (int nj = 0; nj < NJ; ++nj)
            #pragma unroll
            for (int q = 0; q < 4; ++q) acc[mi][nj][q] = 0.0f;

    const int nt = K >> 6;

    if (PIPE == 0) {
        stage(0, lds);
        __syncthreads();
        const u16* la = lds;
        const u16* lb = lds + BM * 64;
        i32x4 af[MI][2], bfr[NJ][2];
        #pragma unroll
        for (int mi = 0; mi < MI; ++mi)
            #pragma unroll
            for (int kk = 0; kk < 2; ++kk) {
                const int row = wr * (BM / 2) + mi * 16 + l16;
                af[mi][kk] = *(const i32x4*)&la[row * 64 + ((((kk << 2) + l4) ^ (row & 7)) << 3)];
            }
        #pragma unroll
        for (int nj = 0; nj < NJ; ++nj)
            #pragma unroll
            for (int kk = 0; kk < 2; ++kk) {
                const int row = wc * (BN / 2) + nj * 16 + l16;
                bfr[nj][kk] = *(const i32x4*)&lb[row * 64 + ((((kk << 2) + l4) ^ (row & 7)) << 3)];
            }
        #pragma unroll
        for (int kk = 0; kk < 2; ++kk)
            #pragma unroll
            for (int mi = 0; mi < MI; ++mi)
                #pragma unroll
                for (int nj = 0; nj < NJ; ++nj)
                    mfma_bf16(acc[mi][nj], af[mi][kk], bfr[nj][kk]);
    } else {
        stage(0, lds);
        if (nt > 1) stage(1, lds + BUFE);
        for (int tt = 0; tt < nt; ++tt) {
            if (tt + 1 < nt) {
                if constexpr (LPS == 8) asm volatile("s_waitcnt vmcnt(8)" ::: "memory");
                else if constexpr (LPS == 7) asm volatile("s_waitcnt vmcnt(7)" ::: "memory");
                else if constexpr (LPS == 6) asm volatile("s_waitcnt vmcnt(6)" ::: "memory");
                else asm volatile("s_waitcnt vmcnt(5)" ::: "memory");
            } else {
                asm volatile("s_waitcnt vmcnt(0)" ::: "memory");
            }
            __builtin_amdgcn_s_barrier();
            u16* la = lds + (tt & 1) * BUFE;
            const u16* lb = la + BM * 64;
            i32x4 af[MI][2], bfr[NJ][2];
            #pragma unroll
            for (int mi = 0; mi < MI; ++mi)
                #pragma unroll
                for (int kk = 0; kk < 2; ++kk) {
                    const int row = wr * (BM / 2) + mi * 16 + l16;
                    af[mi][kk] = *(const i32x4*)&la[row * 64 + ((((kk << 2) + l4) ^ (row & 7)) << 3)];
                }
            #pragma unroll
            for (int nj = 0; nj < NJ; ++nj)
                #pragma unroll
                for (int kk = 0; kk < 2; ++kk) {
                    const int row = wc * (BN / 2) + nj * 16 + l16;
                    bfr[nj][kk] = *(const i32x4*)&lb[row * 64 + ((((kk << 2) + l4) ^ (row & 7)) << 3)];
                }
            asm volatile("s_waitcnt lgkmcnt(0)" ::: "memory");
            __builtin_amdgcn_sched_barrier(0);
            __builtin_amdgcn_s_barrier();
            if (tt + 2 < nt) stage(tt + 2, la);
            #pragma unroll
            for (int kk = 0; kk < 2; ++kk)
                #pragma unroll
                for (int mi = 0; mi < MI; ++mi)
                    #pragma unroll
                    for (int nj = 0; nj < NJ; ++nj)
                        mfma_bf16(acc[mi][nj], af[mi][kk], bfr[nj][kk]);
        }
        __syncthreads();
    }
    __builtin_amdgcn_sched_barrier(0);
    asm volatile("s_nop 7");
    asm volatile("s_nop 7");
    __builtin_amdgcn_sched_barrier(0);

    if (EPI == 1 || EPI == 3) mask += (long)zb * S_;
    const long cbase = zb * sCb + zh * sCh;

    float red[MI][4];
    if (EPI == 3) {
        #pragma unroll
        for (int mi = 0; mi < MI; ++mi)
            #pragma unroll
            for (int r = 0; r < 4; ++r) red[mi][r] = -INFINITY;
    }

    #pragma unroll
    for (int mi = 0; mi < MI; ++mi) {
        #pragma unroll
        for (int nj = 0; nj < NJ; ++nj) {
            const int gn = n0 + wc * (BN / 2) + nj * 16 + l16;
            const float bv = ((EPI == 0 || EPI == 4 || EPI == 7) && bias) ? bias[gn] : 0.0f;
            float invf = 0.0f;
            if (EPI == 4) invf = exp2f(-(float)((gn & 63) >> 1) * 0.41524101186092503f);
            #pragma unroll
            for (int r = 0; r < 4; ++r) {
                const int gm = m0 + wr * (BM / 2) + mi * 16 + l4 * 4 + r;
                float v = acc[mi][nj][r];
                const long cidx = cbase + (long)gm * ldc + gn;
                if (EPI == 0) {
                    v += bv;
                    if (OBF) ((u16*)Cv)[cidx] = f2bf(v);
                    else     ((float*)Cv)[cidx] = v;
                } else if (EPI == 7) {
                    v += bv;
                    const u16 bfv = f2bf(v);
                    ((u16*)Cv)[cidx] = bfv;
                    if (gn >= 2 * H_) {
                        const int hh = (gn - 2 * H_) / HD_;
                        const int dd = (gn - 2 * H_) - hh * HD_;
                        const int bb = gm >> 10, ss = gm & (S_ - 1);
                        ((u16*)aux)[((long)(bb * NH_ + hh) * HD_ + dd) * S_ + ss] = bfv;
                    }
                } else if (EPI == 1 || EPI == 3) {
                    const float pad = mask[gn];
                    v = v * pad - (1.0f - pad) * 1e12f;
                    if (gm > gn) v -= 1e12f;
                    v *= 0.125f;
                    ((float*)Cv)[cidx] = v;
                    if (EPI == 3) red[mi][r] = fmaxf(red[mi][r], v);
                } else { // EPI == 4
                    v += bv;
                    const int sp = gm & (S_ - 1);
                    float sn, cs;
                    __sincosf((float)sp * invf, &sn, &cs);
                    const float pv = __shfl_xor(v, 1, 64);
                    v = (gn & 1) ? fmaf(v, cs, pv * sn) : fmaf(v, cs, -pv * sn);
                    ((u16*)Cv)[cidx] = f2bf(v);
                }
            }
        }
    }

    if (EPI == 3) {
        #pragma unroll
        for (int mi = 0; mi < MI; ++mi) {
            #pragma unroll
            for (int r = 0; r < 4; ++r) {
                float m = red[mi][r];
                m = fmaxf(m, __shfl_xor(m, 1, 64));
                m = fmaxf(m, __shfl_xor(m, 2, 64));
                m = fmaxf(m, __shfl_xor(m, 4, 64));
                m = fmaxf(m, __shfl_xor(m, 8, 64));
                if (l16 == 0) {
                    const int gm = m0 + wr * (BM / 2) + mi * 16 + l4 * 4 + r;
                    aux[((long)z * S_ + gm) * 16 + bx * 2 + wc] = m;
                }
            }
        }
    }
}

// ---------------------------------------------------------------------------
// Fused flash-style attention: ctx = softmax(QK^T/sqrt(HD), keypad) @ V.
// One block = 64 Q-rows of one (b,h). 4 waves 2x2. Q cached in registers.
// 16 KV-tiles of 64 keys: stage K + V^T -> S-MFMA -> exp + P->LDS + rowsum
// -> PV-MFMA accumulate. Final: ctx /= rowsum, bf16 store.
// exp without max-subtraction (bounded scores; identical to prior EPI-5 path).
// ---------------------------------------------------------------------------
__global__ __launch_bounds__(256) void attn_fused(
    const u16* __restrict__ qkv, const u16* __restrict__ vt,
    const float* __restrict__ mask, u16* __restrict__ ctx, float qscale)
{
    const int z = blockIdx.y;              // b*NH + h
    const int b = z >> 2, h = z & 3;
    const int s0 = blockIdx.x * 64;
    const int t = threadIdx.x;
    const int lane = t & 63, wid = t >> 6;
    const int wr = wid >> 1, wc = wid & 1;
    const int l16 = lane & 15, l4 = lane >> 4;

    __shared__ u16 k_lds[64 * 192];        // [key][d], XOR-swizzled (24 granules/row)
    __shared__ u16 v_lds[192 * 64];        // [d][key], XOR-swizzled (8 granules/row)
    __shared__ u16 p_lds[64 * 64];         // [qrow][key], XOR-swizzled
    __shared__ float rs_lds[2][64];

    // Q fragments cached in registers: rows s0 + wr*32 + mi*16 + l16
    i32x4 qf[2][6];
    {
        const u16* qb = qkv + (long)(b * S_ + s0 + wr * 32 + l16) * H3_ + h * HD_;
        #pragma unroll
        for (int mi = 0; mi < 2; ++mi)
            #pragma unroll
            for (int kk = 0; kk < 6; ++kk)
                qf[mi][kk] = *(const i32x4*)(qb + (long)mi * 16 * H3_ + kk * 32 + l4 * 8);
    }
    asm volatile("s_waitcnt vmcnt(0)" ::: "memory");   // Q resolved; stage counts exact

    f32x4 acc_c[2][6];
    #pragma unroll
    for (int mi = 0; mi < 2; ++mi)
        #pragma unroll
        for (int nj = 0; nj < 6; ++nj)
            #pragma unroll
            for (int q = 0; q < 4; ++q) acc_c[mi][nj][q] = 0.0f;
    float rs_acc[2][4] = {};

    const float* mrow = mask + (long)b * S_;

    for (int kt = 0; kt < 16; ++kt) {
        const int kv0 = kt * 64;
        // stage K tile: 64 rows x 24 granules
        #pragma unroll
        for (int i = 0; i < 6; ++i) {
            const int e = i * 256 + t;
            const int row = e / 24;
            const int g = e - row * 24;
            const int gs = (g & ~7) | ((g & 7) ^ (row & 7));
            gload16(qkv + (long)(b * S_ + kv0 + row) * H3_ + H_ + h * HD_ + gs * 8,
                    k_lds + e * 8);
        }
        // stage V^T tile: 192 rows x 8 granules
        #pragma unroll
        for (int i = 0; i < 6; ++i) {
            const int e = i * 256 + t;
            const int row = e >> 3, g = e & 7;
            const int gs = g ^ (row & 7);
            gload16(vt + ((long)z * HD_ + row) * S_ + kv0 + gs * 8,
                    v_lds + e * 8);
        }
        asm volatile("s_waitcnt vmcnt(6)" ::: "memory");   // K done (V in flight)
        __builtin_amdgcn_s_barrier();

        // S = Q K^T (64x64; wave tile 32x32)
        f32x4 acc_s[2][2];
        #pragma unroll
        for (int mi = 0; mi < 2; ++mi)
            #pragma unroll
            for (int nj = 0; nj < 2; ++nj)
                #pragma unroll
                for (int q = 0; q < 4; ++q) acc_s[mi][nj][q] = 0.0f;
        #pragma unroll
        for (int kk = 0; kk < 6; ++kk) {
            #pragma unroll
            for (int nj = 0; nj < 2; ++nj) {
                const int row = wc * 32 + nj * 16 + l16;
                const int g = kk * 4 + l4;
                const int gs = (g & ~7) | ((g & 7) ^ (row & 7));
                const i32x4 kf = *(const i32x4*)&k_lds[row * 192 + gs * 8];
                #pragma unroll
                for (int mi = 0; mi < 2; ++mi)
                    mfma_bf16(acc_s[mi][nj], qf[mi][kk], kf);
            }
        }
        __builtin_amdgcn_sched_barrier(0);
        asm volatile("s_nop 7");
        asm volatile("s_nop 7");
        __builtin_amdgcn_sched_barrier(0);

        // exp epilogue: P -> LDS (swizzled), rowsum partials
        float rsp[2][4] = {};
        #pragma unroll
        for (int mi = 0; mi < 2; ++mi) {
            #pragma unroll
            for (int nj = 0; nj < 2; ++nj) {
                const int coll = wc * 32 + nj * 16 + l16;
                const float mk = mrow[kv0 + coll];
                #pragma unroll
                for (int r = 0; r < 4; ++r) {
                    const int rowl = wr * 32 + mi * 16 + l4 * 4 + r;
                    float tv = 0.0f;
                    if (mk != 0.0f) tv = __expf(acc_s[mi][nj][r] * qscale);
                    const int gs = (coll >> 3) ^ (rowl & 7);
                    p_lds[rowl * 64 + gs * 8 + (coll & 7)] = f2bf(tv);
                    rsp[mi][r] += tv;
                }
            }
        }
        #pragma unroll
        for (int mi = 0; mi < 2; ++mi)
            #pragma unroll
            for (int r = 0; r < 4; ++r) {
                float v = rsp[mi][r];
                v += __shfl_xor(v, 1, 64);
                v += __shfl_xor(v, 2, 64);
                v += __shfl_xor(v, 4, 64);
                v += __shfl_xor(v, 8, 64);
                rs_acc[mi][r] += v;
            }

        asm volatile("s_waitcnt vmcnt(0)" ::: "memory");   // V done
        __builtin_amdgcn_s_barrier();                      // P + V visible

        // PV: ctx += P @ V  (wave tile 32 rows x 96 d)
        #pragma unroll
        for (int kk = 0; kk < 2; ++kk) {
            i32x4 pf[2];
            #pragma unroll
            for (int mi = 0; mi < 2; ++mi) {
                const int row = wr * 32 + mi * 16 + l16;
                const int gs = (kk * 4 + l4) ^ (row & 7);
                pf[mi] = *(const i32x4*)&p_lds[row * 64 + gs * 8];
            }
            #pragma unroll
            for (int nj = 0; nj < 6; ++nj) {
                const int row = wc * 96 + nj * 16 + l16;
                const int gs = (kk * 4 + l4) ^ (row & 7);
                const i32x4 vf = *(const i32x4*)&v_lds[row * 64 + gs * 8];
                #pragma unroll
                for (int mi = 0; mi < 2; ++mi)
                    mfma_bf16(acc_c[mi][nj], pf[mi], vf);
            }
        }
        __builtin_amdgcn_s_barrier();                      // reads done; next stage may overwrite
    }

    __builtin_amdgcn_sched_barrier(0);
    asm volatile("s_nop 7");
    asm volatile("s_nop 7");
    __builtin_amdgcn_sched_barrier(0);

    // combine rowsums across wc halves
    if (l16 == 0) {
        #pragma unroll
        for (int mi = 0; mi < 2; ++mi)
            #pragma unroll
            for (int r = 0; r < 4; ++r)
                rs_lds[wc][wr * 32 + mi * 16 + l4 * 4 + r] = rs_acc[mi][r];
    }
    __syncthreads();

    #pragma unroll
    for (int mi = 0; mi < 2; ++mi) {
        #pragma unroll
        for (int r = 0; r < 4; ++r) {
            const int rowl = wr * 32 + mi * 16 + l4 * 4 + r;
            const float inv = 1.0f / (rs_lds[0][rowl] + rs_lds[1][rowl]);
            #pragma unroll
            for (int nj = 0; nj < 6; ++nj) {
                const int d = wc * 96 + nj * 16 + l16;
                ctx[(long)(b * S_ + s0 + rowl) * H_ + h * HD_ + d] =
                    f2bf(acc_c[mi][nj][r] * inv);
            }
        }
    }
}

// ---------------------------------------------------------------------------
// Fused fp32->bf16 cast of hs + 5 weight matrices. 1024 elems per block.
// ---------------------------------------------------------------------------
__global__ __launch_bounds__(256) void cast_all(
    const float* __restrict__ hs, const float* __restrict__ ipw,
    const float* __restrict__ opw, const float* __restrict__ gw,
    const float* __restrict__ entw, const float* __restrict__ relw,
    u16* hs_o, u16* ipw_o, u16* opw_o, u16* gw_o, u16* entw_o, u16* relw_o)
{
    const int blk = blockIdx.x;
    const float* in; u16* out; long base;
    if      (blk < 3072) { in = hs;   out = hs_o;   base = (long)blk * 1024; }
    else if (blk < 4800) { in = ipw;  out = ipw_o;  base = (long)(blk - 3072) * 1024; }
    else if (blk < 5376) { in = opw;  out = opw_o;  base = (long)(blk - 4800) * 1024; }
    else if (blk < 5952) { in = gw;   out = gw_o;   base = (long)(blk - 5376) * 1024; }
    else if (blk < 6816) { in = entw; out = entw_o; base = (long)(blk - 5952) * 1024; }
    else                 { in = relw; out = relw_o; base = (long)(blk - 6816) * 1024; }
    const long idx = base + (long)threadIdx.x * 4;
    const float4 v = *(const float4*)&in[idx];
    ushort4 o; o.x = f2bf(v.x); o.y = f2bf(v.y); o.z = f2bf(v.z); o.w = f2bf(v.w);
    *(ushort4*)&out[idx] = o;
}

// ---------------------------------------------------------------------------
// x = hs + sigmoid(gl)*ao ; LayerNorm -> enh fp32 (d_out) + relh[:768] bf16
// ---------------------------------------------------------------------------
__global__ __launch_bounds__(256) void gate_ln_bf(
    const float* __restrict__ hs, const u16* __restrict__ aogl,
    const float* __restrict__ g, const float* __restrict__ bta,
    float* __restrict__ enh, u16* __restrict__ relh)
{
    const long row = blockIdx.x;
    const float* hrow = hs + row * H_;
    const u16* arow = aogl + row * (2 * H_);
    const int tid = threadIdx.x;
    float x[3];
    float sum = 0.0f, sq = 0.0f;
    #pragma unroll
    for (int i = 0; i < 3; ++i) {
        const int j = tid + i * 256;
        const float a = bf2f(arow[j]);
        const float gt = 1.0f / (1.0f + __expf(-bf2f(arow[H_ + j])));
        const float xv = hrow[j] + gt * a;
        x[i] = xv; sum += xv; sq += xv * xv;
    }
    __shared__ float sm[8];
    #pragma unroll
    for (int o = 32; o > 0; o >>= 1) {
        sum += __shfl_xor(sum, o, 64);
        sq  += __shfl_xor(sq, o, 64);
    }
    const int lane = tid & 63, wid = tid >> 6;
    if (lane == 0) { sm[wid] = sum; sm[4 + wid] = sq; }
    __syncthreads();
    sum = sm[0] + sm[1] + sm[2] + sm[3];
    sq  = sm[4] + sm[5] + sm[6] + sm[7];
    const float mu = sum * (1.0f / (float)H_);
    float var = sq * (1.0f / (float)H_) - mu * mu;
    var = fmaxf(var, 0.0f);
    const float inv = 1.0f / sqrtf(var + 1e-5f);
    #pragma unroll
    for (int i = 0; i < 3; ++i) {
        const int j = tid + i * 256;
        const float o = (x[i] - mu) * inv * g[j] + bta[j];
        enh[row * H_ + j] = o;
        relh[row * (2 * H_) + j] = f2bf(o);
    }
}

// ---------------------------------------------------------------------------
// Fused: prior[t] = max over 16 partials; relh[:,768:] = relu(prior@pw^T+pb)
// ---------------------------------------------------------------------------
__global__ __launch_bounds__(256) void prior_fused(
    const float* __restrict__ pmax, const float* __restrict__ pw,
    const float* __restrict__ pb, u16* __restrict__ relh)
{
    const int row = blockIdx.x;               // b*S + m
    const int b = row >> 10, m = row & (S_ - 1);
    __shared__ float pr[E_];
    const int tid = threadIdx.x;
    if (tid < E_) {
        const float* pp = pmax + ((long)(b * E_ + tid) * S_ + m) * 16;
        float mx = -INFINITY;
        #pragma unroll
        for (int i = 0; i < 16; ++i) mx = fmaxf(mx, pp[i]);
        pr[tid] = mx;
    }
    __syncthreads();
    float p[E_];
    #pragma unroll
    for (int e = 0; e < E_; ++e) p[e] = pr[e];
    u16* orow = relh + (long)row * (2 * H_) + H_;
    #pragma unroll
    for (int i = 0; i < 3; ++i) {
        const int j = tid + i * 256;
        float a = pb[j];
        #pragma unroll
        for (int e = 0; e < E_; ++e) a = fmaf(p[e], pw[j * E_ + e], a);
        orow[j] = f2bf(fmaxf(a, 0.0f));
    }
}

// ---------------------------------------------------------------------------
extern "C" void kernel_launch(void* const* d_in, const int* in_sizes, int n_in,
                              void* d_out, int out_size, void* d_ws, size_t ws_size,
                              hipStream_t stream)
{
    const float* hs   = (const float*)d_in[0];
    const float* mask = (const float*)d_in[1];
    const float* ipw  = (const float*)d_in[2];
    const float* ipb  = (const float*)d_in[3];
    const float* opw  = (const float*)d_in[4];
    const float* opb  = (const float*)d_in[5];
    const float* gw   = (const float*)d_in[6];
    const float* gb   = (const float*)d_in[7];
    const float* lng  = (const float*)d_in[8];
    const float* lnb  = (const float*)d_in[9];
    const float* entw = (const float*)d_in[10];
    const float* entb = (const float*)d_in[11];
    const float* prw  = (const float*)d_in[12];
    const float* prb  = (const float*)d_in[13];
    const float* relw = (const float*)d_in[14];
    const float* relb = (const float*)d_in[15];
    float* out = (float*)d_out;
    char* base = (char*)d_ws;

    // ws layout (bytes)
    u16* ipw_bf  = (u16*)(base + 0);          // 3,538,944
    u16* opw_bf  = (u16*)(base + 3538944);    // 1,179,648  } contiguous pair ->
    u16* gw_bf   = (u16*)(base + 4718592);    // 1,179,648  } combined [1536][768]
    u16* entw_bf = (u16*)(base + 5898240);    // 1,769,472
    u16* relw_bf = (u16*)(base + 7667712);    // 4,718,592
    u16* hs_bf   = (u16*)(base + 12386304);   // 6,291,456
    u16* qkv_bf  = (u16*)(base + 18677760);   // 18,874,368 [dead after attn]
    u16* vt_bf   = (u16*)(base + 37552128);   // 6,291,456  [dead after attn]
    u16* ctx_bf  = (u16*)(base + 77398016);   // 6,291,456
    u16* aogl_bf = (u16*)(base + 83689472);   // 12,582,912
    float* bias2 = (float*)(base + 96272384); //      6,144 (opb|gb)
    float* pmax  = (float*)(base + 97329152); //  2,359,296
    u16* relh_bf = (u16*)(base + 43843584);   // 12,582,912
    u16* projr   = (u16*)(base + 56426496);   // 12,582,912
    float* enh   = out + OUT_ENH_OFF;

    const float qscale = 0.07216878364870323f; // 1/sqrt(192)

    // combined out_proj|gate bias
    hipMemcpyAsync(bias2, opb, H_ * sizeof(float), hipMemcpyDeviceToDevice, stream);
    hipMemcpyAsync(bias2 + H_, gb, H_ * sizeof(float), hipMemcpyDeviceToDevice, stream);

    // 0. casts
    cast_all<<<9120, 256, 0, stream>>>(hs, ipw, opw, gw, entw, relw,
                                       hs_bf, ipw_bf, opw_bf, gw_bf, entw_bf, relw_bf);

    // 1. qkv = hs @ in_proj_w.T + b (4096 x 2304, K=768) + fused V-transpose
    gemm_mfma<128,96,7,1,1><<<dim3(24, 32, 1), 256, 0, stream>>>(
        hs_bf, ipw_bf, ipb, qkv_bf, H_, H_, H_, H3_, 1,
        0,0,0,0,0,0, nullptr, 0.0f, (float*)vt_bf);

    // 2. fused attention: ctx = softmax(QK^T) @ V
    attn_fused<<<dim3(16, 16), 256, 0, stream>>>(
        qkv_bf, vt_bf, mask, ctx_bf, qscale);

    // 3. [attn_out | gate_lin] = ctx @ [opw|gw]^T + [opb|gb]  (4096 x 1536, K=768)
    gemm_mfma<128,96,0,1,1><<<dim3(16, 32, 1), 256, 0, stream>>>(
        ctx_bf, opw_bf, bias2, aogl_bf, H_, H_, H_, 2 * H_, 1,
        0,0,0,0,0,0, nullptr, 0.0f, nullptr);

    // 4. enhanced = LN(hs + sigmoid(gl)*ao) -> enh fp32 + relh[:768]
    gate_ln_bf<<<MBS_, 256, 0, stream>>>(hs, aogl_bf, lng, lnb, enh, relh_bf);

    // 5. ent projection + fused RoPE (4096 x 1152, K=768) -> projr bf16
    gemm_mfma<64,96,4,1,1><<<dim3(12, 64, 1), 256, 0, stream>>>(
        relh_bf, entw_bf, entb, projr, H_, 2 * H_, H_, E_ * 2 * D_, 1,
        0,0,0,0,0,0, nullptr, 0.0f, nullptr);

    // 6. ent logits + fused rowmax partials -> out[0], pmax   (K=64)
    gemm_mfma<128,128,3,0,0><<<dim3(8, 8, B_ * E_), 256, 0, stream>>>(
        projr, projr + D_, nullptr, out, D_, E_ * 2 * D_, E_ * 2 * D_, S_, E_,
        (long)S_ * E_ * 2 * D_, 2 * D_, (long)S_ * E_ * 2 * D_, 2 * D_,
        (long)E_ * S_ * S_, (long)S_ * S_, mask, 0.0f, pmax);

    // 7. prior reduce + feat -> relh[:, 768:]
    prior_fused<<<MBS_, 256, 0, stream>>>(pmax, prw, prb, relh_bf);

    // 8. rel projection + fused RoPE (4096 x 1536, K=1536) -> projr bf16
    gemm_mfma<128,96,4,1,1><<<dim3(16, 32, 1), 256, 0, stream>>>(
        relh_bf, relw_bf, relb, projr, 2 * H_, 2 * H_, 2 * H_, R_ * 2 * D_, 1,
        0,0,0,0,0,0, nullptr, 0.0f, nullptr);

    // 9. rel logits -> out[1]   (48 x 1024 x 1024, K=64)
    gemm_mfma<128,128,1,0,0><<<dim3(8, 8, B_ * R_), 256, 0, stream>>>(
        projr, projr + D_, nullptr, out + OUT_REL_OFF, D_, R_ * 2 * D_, R_ * 2 * D_, S_, R_,
        (long)S_ * R_ * 2 * D_, 2 * D_, (long)S_ * R_ * 2 * D_, 2 * D_,
        (long)R_ * S_ * S_, (long)S_ * S_, mask, 0.0f, nullptr);

    (void)in_sizes; (void)n_in; (void)out_size; (void)ws_size;
}

// Round 9
// 246.896 us; speedup vs baseline: 1.0433x; 1.0433x over previous
//
#include <hip/hip_runtime.h>
#include <math.h>

#define H_   768
#define NH_  4
#define HD_  192
#define E_   9
#define R_   12
#define D_   64
#define B_   4
#define S_   1024
#define H3_  (3 * H_)
#define MBS_ (B_ * S_)

typedef unsigned short u16;
typedef __attribute__((ext_vector_type(4))) int   i32x4;
typedef __attribute__((ext_vector_type(4))) float f32x4;

static const long OUT_REL_OFF = (long)B_ * E_ * S_ * S_;                    // 37,748,736
static const long OUT_ENH_OFF = OUT_REL_OFF + (long)B_ * R_ * S_ * S_;      // 88,080,384

__device__ __forceinline__ u16 f2bf(float f) {
    unsigned u = __builtin_bit_cast(unsigned, f);
    return (u16)((u + 0x7fffu + ((u >> 16) & 1u)) >> 16);
}
__device__ __forceinline__ float bf2f(u16 h) {
    return __builtin_bit_cast(float, (unsigned)h << 16);
}
__device__ __forceinline__ void gload16(const u16* g, u16* l) {
    __builtin_amdgcn_global_load_lds(
        (__attribute__((address_space(1))) void*)g,
        (__attribute__((address_space(3))) void*)l, 16, 0, 0);
}
__device__ __forceinline__ void mfma_bf16(f32x4& acc, i32x4 a, i32x4 b) {
    asm volatile("v_mfma_f32_16x16x32_bf16 %0, %1, %2, %0"
                 : "+v"(acc) : "v"(a), "v"(b));
}

// ---------------------------------------------------------------------------
// bf16 MFMA GEMM, NT (unchanged from round 8).
// ---------------------------------------------------------------------------
template<int BM, int BN, int EPI, int OBF, int PIPE>
__global__ __launch_bounds__(256) void gemm_mfma(
    const u16* __restrict__ A, const u16* __restrict__ Bw,
    const float* __restrict__ bias, void* __restrict__ Cv,
    int K, int lda, int ldb, int ldc, int nh,
    long sAb, long sAh, long sBb, long sBh, long sCb, long sCh,
    const float* __restrict__ mask, float scale, float* __restrict__ aux)
{
    constexpr int MI = BM / 32, NJ = BN / 32;
    constexpr int BUFE = (BM + BN) * 64;
    constexpr int LPS  = BM / 32 + BN / 32;
    const int z = blockIdx.z;
    const int zb = z / nh, zh = z - zb * nh;
    A  += zb * sAb + zh * sAh;
    Bw += zb * sBb + zh * sBh;

    const int gx = gridDim.x, gy = gridDim.y;
    int id = blockIdx.y * gx + blockIdx.x;
    const int nwg = gx * gy;
    if ((nwg & 7) == 0) id = (id & 7) * (nwg >> 3) + (id >> 3);
    const int bx = id % gx, by = id / gx;
    const int m0 = by * BM, n0 = bx * BN;

    __shared__ u16 lds[(PIPE ? 2 : 1) * BUFE];

    const int t = threadIdx.x;
    const int lane = t & 63, wid = t >> 6;
    const int wr = wid >> 1, wc = wid & 1;
    const int l16 = lane & 15, l4 = lane >> 4;

    auto stage = [&](int kt, u16* la) {
        u16* lb = la + BM * 64;
        const int k0 = kt << 6;
        #pragma unroll
        for (int i = 0; i < BM / 32; ++i) {
            const int e = i * 256 + t;
            const int row = e >> 3;
            const int c = ((e & 7) ^ (row & 7)) << 3;
            gload16(A + (long)(m0 + row) * lda + k0 + c, la + e * 8);
        }
        #pragma unroll
        for (int i = 0; i < BN / 32; ++i) {
            const int e = i * 256 + t;
            const int row = e >> 3;
            const int c = ((e & 7) ^ (row & 7)) << 3;
            gload16(Bw + (long)(n0 + row) * ldb + k0 + c, lb + e * 8);
        }
    };

    f32x4 acc[MI][NJ];
    #pragma unroll
    for (int mi = 0; mi < MI; ++mi)
        #pragma unroll
        for (int nj = 0; nj < NJ; ++nj)
            #pragma unroll
            for (int q = 0; q < 4; ++q) acc[mi][nj][q] = 0.0f;

    const int nt = K >> 6;

    if (PIPE == 0) {
        stage(0, lds);
        __syncthreads();
        const u16* la = lds;
        const u16* lb = lds + BM * 64;
        i32x4 af[MI][2], bfr[NJ][2];
        #pragma unroll
        for (int mi = 0; mi < MI; ++mi)
            #pragma unroll
            for (int kk = 0; kk < 2; ++kk) {
                const int row = wr * (BM / 2) + mi * 16 + l16;
                af[mi][kk] = *(const i32x4*)&la[row * 64 + ((((kk << 2) + l4) ^ (row & 7)) << 3)];
            }
        #pragma unroll
        for (int nj = 0; nj < NJ; ++nj)
            #pragma unroll
            for (int kk = 0; kk < 2; ++kk) {
                const int row = wc * (BN / 2) + nj * 16 + l16;
                bfr[nj][kk] = *(const i32x4*)&lb[row * 64 + ((((kk << 2) + l4) ^ (row & 7)) << 3)];
            }
        #pragma unroll
        for (int kk = 0; kk < 2; ++kk)
            #pragma unroll
            for (int mi = 0; mi < MI; ++mi)
                #pragma unroll
                for (int nj = 0; nj < NJ; ++nj)
                    mfma_bf16(acc[mi][nj], af[mi][kk], bfr[nj][kk]);
    } else {
        stage(0, lds);
        if (nt > 1) stage(1, lds + BUFE);
        for (int tt = 0; tt < nt; ++tt) {
            if (tt + 1 < nt) {
                if constexpr (LPS == 8) asm volatile("s_waitcnt vmcnt(8)" ::: "memory");
                else if constexpr (LPS == 7) asm volatile("s_waitcnt vmcnt(7)" ::: "memory");
                else if constexpr (LPS == 6) asm volatile("s_waitcnt vmcnt(6)" ::: "memory");
                else asm volatile("s_waitcnt vmcnt(5)" ::: "memory");
            } else {
                asm volatile("s_waitcnt vmcnt(0)" ::: "memory");
            }
            __builtin_amdgcn_s_barrier();
            u16* la = lds + (tt & 1) * BUFE;
            const u16* lb = la + BM * 64;
            i32x4 af[MI][2], bfr[NJ][2];
            #pragma unroll
            for (int mi = 0; mi < MI; ++mi)
                #pragma unroll
                for (int kk = 0; kk < 2; ++kk) {
                    const int row = wr * (BM / 2) + mi * 16 + l16;
                    af[mi][kk] = *(const i32x4*)&la[row * 64 + ((((kk << 2) + l4) ^ (row & 7)) << 3)];
                }
            #pragma unroll
            for (int nj = 0; nj < NJ; ++nj)
                #pragma unroll
                for (int kk = 0; kk < 2; ++kk) {
                    const int row = wc * (BN / 2) + nj * 16 + l16;
                    bfr[nj][kk] = *(const i32x4*)&lb[row * 64 + ((((kk << 2) + l4) ^ (row & 7)) << 3)];
                }
            asm volatile("s_waitcnt lgkmcnt(0)" ::: "memory");
            __builtin_amdgcn_sched_barrier(0);
            __builtin_amdgcn_s_barrier();
            if (tt + 2 < nt) stage(tt + 2, la);
            #pragma unroll
            for (int kk = 0; kk < 2; ++kk)
                #pragma unroll
                for (int mi = 0; mi < MI; ++mi)
                    #pragma unroll
                    for (int nj = 0; nj < NJ; ++nj)
                        mfma_bf16(acc[mi][nj], af[mi][kk], bfr[nj][kk]);
        }
        __syncthreads();
    }
    __builtin_amdgcn_sched_barrier(0);
    asm volatile("s_nop 7");
    asm volatile("s_nop 7");
    __builtin_amdgcn_sched_barrier(0);

    if (EPI == 1 || EPI == 3) mask += (long)zb * S_;
    const long cbase = zb * sCb + zh * sCh;

    float red[MI][4];
    if (EPI == 3) {
        #pragma unroll
        for (int mi = 0; mi < MI; ++mi)
            #pragma unroll
            for (int r = 0; r < 4; ++r) red[mi][r] = -INFINITY;
    }

    #pragma unroll
    for (int mi = 0; mi < MI; ++mi) {
        #pragma unroll
        for (int nj = 0; nj < NJ; ++nj) {
            const int gn = n0 + wc * (BN / 2) + nj * 16 + l16;
            const float bv = ((EPI == 0 || EPI == 4 || EPI == 7) && bias) ? bias[gn] : 0.0f;
            float invf = 0.0f;
            if (EPI == 4) invf = exp2f(-(float)((gn & 63) >> 1) * 0.41524101186092503f);
            #pragma unroll
            for (int r = 0; r < 4; ++r) {
                const int gm = m0 + wr * (BM / 2) + mi * 16 + l4 * 4 + r;
                float v = acc[mi][nj][r];
                const long cidx = cbase + (long)gm * ldc + gn;
                if (EPI == 0) {
                    v += bv;
                    if (OBF) ((u16*)Cv)[cidx] = f2bf(v);
                    else     ((float*)Cv)[cidx] = v;
                } else if (EPI == 7) {
                    v += bv;
                    const u16 bfv = f2bf(v);
                    ((u16*)Cv)[cidx] = bfv;
                    if (gn >= 2 * H_) {
                        const int hh = (gn - 2 * H_) / HD_;
                        const int dd = (gn - 2 * H_) - hh * HD_;
                        const int bb = gm >> 10, ss = gm & (S_ - 1);
                        ((u16*)aux)[((long)(bb * NH_ + hh) * HD_ + dd) * S_ + ss] = bfv;
                    }
                } else if (EPI == 1 || EPI == 3) {
                    const float pad = mask[gn];
                    v = v * pad - (1.0f - pad) * 1e12f;
                    if (gm > gn) v -= 1e12f;
                    v *= 0.125f;
                    ((float*)Cv)[cidx] = v;
                    if (EPI == 3) red[mi][r] = fmaxf(red[mi][r], v);
                } else { // EPI == 4
                    v += bv;
                    const int sp = gm & (S_ - 1);
                    float sn, cs;
                    __sincosf((float)sp * invf, &sn, &cs);
                    const float pv = __shfl_xor(v, 1, 64);
                    v = (gn & 1) ? fmaf(v, cs, pv * sn) : fmaf(v, cs, -pv * sn);
                    ((u16*)Cv)[cidx] = f2bf(v);
                }
            }
        }
    }

    if (EPI == 3) {
        #pragma unroll
        for (int mi = 0; mi < MI; ++mi) {
            #pragma unroll
            for (int r = 0; r < 4; ++r) {
                float m = red[mi][r];
                m = fmaxf(m, __shfl_xor(m, 1, 64));
                m = fmaxf(m, __shfl_xor(m, 2, 64));
                m = fmaxf(m, __shfl_xor(m, 4, 64));
                m = fmaxf(m, __shfl_xor(m, 8, 64));
                if (l16 == 0) {
                    const int gm = m0 + wr * (BM / 2) + mi * 16 + l4 * 4 + r;
                    aux[((long)z * S_ + gm) * 16 + bx * 2 + wc] = m;
                }
            }
        }
    }
}

// ---------------------------------------------------------------------------
// Fused flash-style attention, QBLK=32: grid 32x16 = 512 blocks (2+/CU).
// 4 waves, layout 1x4: S-phase each wave owns a 16-key slice; PV-phase each
// wave owns a 48-wide d-slice. Q (32 rows) replicated in registers per wave.
// ---------------------------------------------------------------------------
__global__ __launch_bounds__(256) void attn_fused(
    const u16* __restrict__ qkv, const u16* __restrict__ vt,
    const float* __restrict__ mask, u16* __restrict__ ctx, float qscale)
{
    const int z = blockIdx.y;              // b*NH + h
    const int b = z >> 2, h = z & 3;
    const int s0 = blockIdx.x * 32;
    const int t = threadIdx.x;
    const int lane = t & 63, w = t >> 6;
    const int l16 = lane & 15, l4 = lane >> 4;

    __shared__ u16 k_lds[64 * 192];        // [key][d], swizzled low-3 granule bits
    __shared__ u16 v_lds[192 * 64];        // [d][key], swizzled
    __shared__ u16 p_lds[32 * 64];         // [qrow][key], swizzled
    __shared__ float rs_lds[4][32];

    // Q fragments (replicated per wave): rows s0 + mi*16 + l16
    i32x4 qf[2][6];
    {
        const u16* qb = qkv + (long)(b * S_ + s0 + l16) * H3_ + h * HD_;
        #pragma unroll
        for (int mi = 0; mi < 2; ++mi)
            #pragma unroll
            for (int kk = 0; kk < 6; ++kk)
                qf[mi][kk] = *(const i32x4*)(qb + (long)mi * 16 * H3_ + kk * 32 + l4 * 8);
    }
    asm volatile("s_waitcnt vmcnt(0)" ::: "memory");   // exact vmcnt bookkeeping below

    f32x4 acc_c[2][3];
    #pragma unroll
    for (int mi = 0; mi < 2; ++mi)
        #pragma unroll
        for (int nj = 0; nj < 3; ++nj)
            #pragma unroll
            for (int q = 0; q < 4; ++q) acc_c[mi][nj][q] = 0.0f;
    float rs_acc[2][4] = {};

    const float* mrow = mask + (long)b * S_;

    for (int kt = 0; kt < 16; ++kt) {
        const int kv0 = kt * 64;
        // stage K tile: 64 rows x 24 granules (6 x 256 threads)
        #pragma unroll
        for (int i = 0; i < 6; ++i) {
            const int e = i * 256 + t;
            const int row = e / 24;
            const int g = e - row * 24;
            const int gs = (g & ~7) | ((g & 7) ^ (row & 7));
            gload16(qkv + (long)(b * S_ + kv0 + row) * H3_ + H_ + h * HD_ + gs * 8,
                    k_lds + e * 8);
        }
        // stage V^T tile: 192 rows x 8 granules
        #pragma unroll
        for (int i = 0; i < 6; ++i) {
            const int e = i * 256 + t;
            const int row = e >> 3, g = e & 7;
            const int gs = g ^ (row & 7);
            gload16(vt + ((long)z * HD_ + row) * S_ + kv0 + gs * 8,
                    v_lds + e * 8);
        }
        asm volatile("s_waitcnt vmcnt(6)" ::: "memory");   // K landed (V in flight)
        __builtin_amdgcn_s_barrier();

        // S = Q K^T : this wave's keys [w*16, w*16+16)
        f32x4 acc_s[2];
        #pragma unroll
        for (int mi = 0; mi < 2; ++mi)
            #pragma unroll
            for (int q = 0; q < 4; ++q) acc_s[mi][q] = 0.0f;
        #pragma unroll
        for (int kk = 0; kk < 6; ++kk) {
            const int krow = w * 16 + l16;
            const int g = kk * 4 + l4;
            const int gs = (g & ~7) | ((g & 7) ^ (krow & 7));
            const i32x4 kf = *(const i32x4*)&k_lds[krow * 192 + gs * 8];
            #pragma unroll
            for (int mi = 0; mi < 2; ++mi)
                mfma_bf16(acc_s[mi], qf[mi][kk], kf);
        }
        __builtin_amdgcn_sched_barrier(0);
        asm volatile("s_nop 7");
        asm volatile("s_nop 7");
        __builtin_amdgcn_sched_barrier(0);

        // exp -> p_lds (swizzled) + rowsum partials
        {
            const int coll = w * 16 + l16;
            const float mk = mrow[kv0 + coll];
            #pragma unroll
            for (int mi = 0; mi < 2; ++mi) {
                float rsp = 0.0f;
                #pragma unroll
                for (int r = 0; r < 4; ++r) {
                    const int rowl = mi * 16 + l4 * 4 + r;
                    float tv = 0.0f;
                    if (mk != 0.0f) tv = __expf(acc_s[mi][r] * qscale);
                    const int gs = (coll >> 3) ^ (rowl & 7);
                    p_lds[rowl * 64 + gs * 8 + (coll & 7)] = f2bf(tv);
                    // accumulate per (rowl) later; per-r partial:
                    rsp = tv;
                    float v = rsp;
                    v += __shfl_xor(v, 1, 64);
                    v += __shfl_xor(v, 2, 64);
                    v += __shfl_xor(v, 4, 64);
                    v += __shfl_xor(v, 8, 64);
                    rs_acc[mi][r] += v;
                }
            }
        }

        asm volatile("s_waitcnt vmcnt(0) lgkmcnt(0)" ::: "memory"); // V + P writes done
        __builtin_amdgcn_sched_barrier(0);
        __builtin_amdgcn_s_barrier();                               // P + V visible

        // PV: ctx += P @ V ; this wave's d-slice [w*48, w*48+48)
        #pragma unroll
        for (int kk = 0; kk < 2; ++kk) {
            i32x4 pf[2];
            #pragma unroll
            for (int mi = 0; mi < 2; ++mi) {
                const int row = mi * 16 + l16;
                const int gs = (kk * 4 + l4) ^ (row & 7);
                pf[mi] = *(const i32x4*)&p_lds[row * 64 + gs * 8];
            }
            #pragma unroll
            for (int nj = 0; nj < 3; ++nj) {
                const int row = w * 48 + nj * 16 + l16;
                const int gs = (kk * 4 + l4) ^ (row & 7);
                const i32x4 vf = *(const i32x4*)&v_lds[row * 64 + gs * 8];
                #pragma unroll
                for (int mi = 0; mi < 2; ++mi)
                    mfma_bf16(acc_c[mi][nj], pf[mi], vf);
            }
        }
        __builtin_amdgcn_s_barrier();      // all reads done; next stage may overwrite
    }

    __builtin_amdgcn_sched_barrier(0);
    asm volatile("s_nop 7");
    asm volatile("s_nop 7");
    __builtin_amdgcn_sched_barrier(0);

    // combine rowsums across the 4 waves
    if (l16 == 0) {
        #pragma unroll
        for (int mi = 0; mi < 2; ++mi)
            #pragma unroll
            for (int r = 0; r < 4; ++r)
                rs_lds[w][mi * 16 + l4 * 4 + r] = rs_acc[mi][r];
    }
    __syncthreads();

    #pragma unroll
    for (int mi = 0; mi < 2; ++mi) {
        #pragma unroll
        for (int r = 0; r < 4; ++r) {
            const int rowl = mi * 16 + l4 * 4 + r;
            const float inv = 1.0f / (rs_lds[0][rowl] + rs_lds[1][rowl] +
                                      rs_lds[2][rowl] + rs_lds[3][rowl]);
            #pragma unroll
            for (int nj = 0; nj < 3; ++nj) {
                const int d = w * 48 + nj * 16 + l16;
                ctx[(long)(b * S_ + s0 + rowl) * H_ + h * HD_ + d] =
                    f2bf(acc_c[mi][nj][r] * inv);
            }
        }
    }
}

// ---------------------------------------------------------------------------
// Fused fp32->bf16 cast of hs + 5 weight matrices + bias2 concat.
// ---------------------------------------------------------------------------
__global__ __launch_bounds__(256) void cast_all(
    const float* __restrict__ hs, const float* __restrict__ ipw,
    const float* __restrict__ opw, const float* __restrict__ gw,
    const float* __restrict__ entw, const float* __restrict__ relw,
    const float* __restrict__ opb, const float* __restrict__ gb,
    u16* hs_o, u16* ipw_o, u16* opw_o, u16* gw_o, u16* entw_o, u16* relw_o,
    float* bias2)
{
    const int blk = blockIdx.x;
    if (blk >= 9120) {
        const float* src = (blk == 9120) ? opb : gb;
        float* dst = bias2 + (blk - 9120) * H_;
        if (threadIdx.x < 192)
            *(float4*)&dst[threadIdx.x * 4] = *(const float4*)&src[threadIdx.x * 4];
        return;
    }
    const float* in; u16* out; long base;
    if      (blk < 3072) { in = hs;   out = hs_o;   base = (long)blk * 1024; }
    else if (blk < 4800) { in = ipw;  out = ipw_o;  base = (long)(blk - 3072) * 1024; }
    else if (blk < 5376) { in = opw;  out = opw_o;  base = (long)(blk - 4800) * 1024; }
    else if (blk < 5952) { in = gw;   out = gw_o;   base = (long)(blk - 5376) * 1024; }
    else if (blk < 6816) { in = entw; out = entw_o; base = (long)(blk - 5952) * 1024; }
    else                 { in = relw; out = relw_o; base = (long)(blk - 6816) * 1024; }
    const long idx = base + (long)threadIdx.x * 4;
    const float4 v = *(const float4*)&in[idx];
    ushort4 o; o.x = f2bf(v.x); o.y = f2bf(v.y); o.z = f2bf(v.z); o.w = f2bf(v.w);
    *(ushort4*)&out[idx] = o;
}

// ---------------------------------------------------------------------------
// x = hs + sigmoid(gl)*ao ; LayerNorm -> enh fp32 (d_out) + relh[:768] bf16
// ---------------------------------------------------------------------------
__global__ __launch_bounds__(256) void gate_ln_bf(
    const float* __restrict__ hs, const u16* __restrict__ aogl,
    const float* __restrict__ g, const float* __restrict__ bta,
    float* __restrict__ enh, u16* __restrict__ relh)
{
    const long row = blockIdx.x;
    const float* hrow = hs + row * H_;
    const u16* arow = aogl + row * (2 * H_);
    const int tid = threadIdx.x;
    float x[3];
    float sum = 0.0f, sq = 0.0f;
    #pragma unroll
    for (int i = 0; i < 3; ++i) {
        const int j = tid + i * 256;
        const float a = bf2f(arow[j]);
        const float gt = 1.0f / (1.0f + __expf(-bf2f(arow[H_ + j])));
        const float xv = hrow[j] + gt * a;
        x[i] = xv; sum += xv; sq += xv * xv;
    }
    __shared__ float sm[8];
    #pragma unroll
    for (int o = 32; o > 0; o >>= 1) {
        sum += __shfl_xor(sum, o, 64);
        sq  += __shfl_xor(sq, o, 64);
    }
    const int lane = tid & 63, wid = tid >> 6;
    if (lane == 0) { sm[wid] = sum; sm[4 + wid] = sq; }
    __syncthreads();
    sum = sm[0] + sm[1] + sm[2] + sm[3];
    sq  = sm[4] + sm[5] + sm[6] + sm[7];
    const float mu = sum * (1.0f / (float)H_);
    float var = sq * (1.0f / (float)H_) - mu * mu;
    var = fmaxf(var, 0.0f);
    const float inv = 1.0f / sqrtf(var + 1e-5f);
    #pragma unroll
    for (int i = 0; i < 3; ++i) {
        const int j = tid + i * 256;
        const float o = (x[i] - mu) * inv * g[j] + bta[j];
        enh[row * H_ + j] = o;
        relh[row * (2 * H_) + j] = f2bf(o);
    }
}

// ---------------------------------------------------------------------------
// Fused: prior[t] = max over 16 partials; relh[:,768:] = relu(prior@pw^T+pb)
// ---------------------------------------------------------------------------
__global__ __launch_bounds__(256) void prior_fused(
    const float* __restrict__ pmax, const float* __restrict__ pw,
    const float* __restrict__ pb, u16* __restrict__ relh)
{
    const int row = blockIdx.x;               // b*S + m
    const int b = row >> 10, m = row & (S_ - 1);
    __shared__ float pr[E_];
    const int tid = threadIdx.x;
    if (tid < E_) {
        const float* pp = pmax + ((long)(b * E_ + tid) * S_ + m) * 16;
        float mx = -INFINITY;
        #pragma unroll
        for (int i = 0; i < 16; ++i) mx = fmaxf(mx, pp[i]);
        pr[tid] = mx;
    }
    __syncthreads();
    float p[E_];
    #pragma unroll
    for (int e = 0; e < E_; ++e) p[e] = pr[e];
    u16* orow = relh + (long)row * (2 * H_) + H_;
    #pragma unroll
    for (int i = 0; i < 3; ++i) {
        const int j = tid + i * 256;
        float a = pb[j];
        #pragma unroll
        for (int e = 0; e < E_; ++e) a = fmaf(p[e], pw[j * E_ + e], a);
        orow[j] = f2bf(fmaxf(a, 0.0f));
    }
}

// ---------------------------------------------------------------------------
extern "C" void kernel_launch(void* const* d_in, const int* in_sizes, int n_in,
                              void* d_out, int out_size, void* d_ws, size_t ws_size,
                              hipStream_t stream)
{
    const float* hs   = (const float*)d_in[0];
    const float* mask = (const float*)d_in[1];
    const float* ipw  = (const float*)d_in[2];
    const float* ipb  = (const float*)d_in[3];
    const float* opw  = (const float*)d_in[4];
    const float* opb  = (const float*)d_in[5];
    const float* gw   = (const float*)d_in[6];
    const float* gb   = (const float*)d_in[7];
    const float* lng  = (const float*)d_in[8];
    const float* lnb  = (const float*)d_in[9];
    const float* entw = (const float*)d_in[10];
    const float* entb = (const float*)d_in[11];
    const float* prw  = (const float*)d_in[12];
    const float* prb  = (const float*)d_in[13];
    const float* relw = (const float*)d_in[14];
    const float* relb = (const float*)d_in[15];
    float* out = (float*)d_out;
    char* base = (char*)d_ws;

    // ws layout (bytes)
    u16* ipw_bf  = (u16*)(base + 0);          // 3,538,944
    u16* opw_bf  = (u16*)(base + 3538944);    // 1,179,648  } contiguous pair ->
    u16* gw_bf   = (u16*)(base + 4718592);    // 1,179,648  } combined [1536][768]
    u16* entw_bf = (u16*)(base + 5898240);    // 1,769,472
    u16* relw_bf = (u16*)(base + 7667712);    // 4,718,592
    u16* hs_bf   = (u16*)(base + 12386304);   // 6,291,456
    u16* qkv_bf  = (u16*)(base + 18677760);   // 18,874,368 [dead after attn]
    u16* vt_bf   = (u16*)(base + 37552128);   // 6,291,456  [dead after attn]
    u16* ctx_bf  = (u16*)(base + 77398016);   // 6,291,456
    u16* aogl_bf = (u16*)(base + 83689472);   // 12,582,912
    float* bias2 = (float*)(base + 96272384); //      6,144 (opb|gb)
    float* pmax  = (float*)(base + 97329152); //  2,359,296
    u16* relh_bf = (u16*)(base + 43843584);   // 12,582,912
    u16* projr   = (u16*)(base + 56426496);   // 12,582,912
    float* enh   = out + OUT_ENH_OFF;

    const float qscale = 0.07216878364870323f; // 1/sqrt(192)

    // 0. casts (+ bias2 concat in blocks 9120/9121)
    cast_all<<<9122, 256, 0, stream>>>(hs, ipw, opw, gw, entw, relw, opb, gb,
                                       hs_bf, ipw_bf, opw_bf, gw_bf, entw_bf, relw_bf,
                                       bias2);

    // 1. qkv = hs @ in_proj_w.T + b (4096 x 2304, K=768) + fused V-transpose
    gemm_mfma<128,96,7,1,1><<<dim3(24, 32, 1), 256, 0, stream>>>(
        hs_bf, ipw_bf, ipb, qkv_bf, H_, H_, H_, H3_, 1,
        0,0,0,0,0,0, nullptr, 0.0f, (float*)vt_bf);

    // 2. fused attention: ctx = softmax(QK^T) @ V   (512 blocks, 2+/CU)
    attn_fused<<<dim3(32, 16), 256, 0, stream>>>(
        qkv_bf, vt_bf, mask, ctx_bf, qscale);

    // 3. [attn_out | gate_lin] = ctx @ [opw|gw]^T + [opb|gb]  (4096 x 1536, K=768)
    gemm_mfma<128,96,0,1,1><<<dim3(16, 32, 1), 256, 0, stream>>>(
        ctx_bf, opw_bf, bias2, aogl_bf, H_, H_, H_, 2 * H_, 1,
        0,0,0,0,0,0, nullptr, 0.0f, nullptr);

    // 4. enhanced = LN(hs + sigmoid(gl)*ao) -> enh fp32 + relh[:768]
    gate_ln_bf<<<MBS_, 256, 0, stream>>>(hs, aogl_bf, lng, lnb, enh, relh_bf);

    // 5. ent projection + fused RoPE (4096 x 1152, K=768) -> projr bf16
    gemm_mfma<64,96,4,1,1><<<dim3(12, 64, 1), 256, 0, stream>>>(
        relh_bf, entw_bf, entb, projr, H_, 2 * H_, H_, E_ * 2 * D_, 1,
        0,0,0,0,0,0, nullptr, 0.0f, nullptr);

    // 6. ent logits + fused rowmax partials -> out[0], pmax   (K=64)
    gemm_mfma<128,128,3,0,0><<<dim3(8, 8, B_ * E_), 256, 0, stream>>>(
        projr, projr + D_, nullptr, out, D_, E_ * 2 * D_, E_ * 2 * D_, S_, E_,
        (long)S_ * E_ * 2 * D_, 2 * D_, (long)S_ * E_ * 2 * D_, 2 * D_,
        (long)E_ * S_ * S_, (long)S_ * S_, mask, 0.0f, pmax);

    // 7. prior reduce + feat -> relh[:, 768:]
    prior_fused<<<MBS_, 256, 0, stream>>>(pmax, prw, prb, relh_bf);

    // 8. rel projection + fused RoPE (4096 x 1536, K=1536) -> projr bf16
    gemm_mfma<128,96,4,1,1><<<dim3(16, 32, 1), 256, 0, stream>>>(
        relh_bf, relw_bf, relb, projr, 2 * H_, 2 * H_, 2 * H_, R_ * 2 * D_, 1,
        0,0,0,0,0,0, nullptr, 0.0f, nullptr);

    // 9. rel logits -> out[1]   (48 x 1024 x 1024, K=64)
    gemm_mfma<128,128,1,0,0><<<dim3(8, 8, B_ * R_), 256, 0, stream>>>(
        projr, projr + D_, nullptr, out + OUT_REL_OFF, D_, R_ * 2 * D_, R_ * 2 * D_, S_, R_,
        (long)S_ * R_ * 2 * D_, 2 * D_, (long)S_ * R_ * 2 * D_, 2 * D_,
        (long)R_ * S_ * S_, (long)S_ * S_, mask, 0.0f, nullptr);

    (void)in_sizes; (void)n_in; (void)out_size; (void)ws_size;
}

// Round 10
// 245.463 us; speedup vs baseline: 1.0493x; 1.0058x over previous
//
#include <hip/hip_runtime.h>
#include <math.h>

#define H_   768
#define NH_  4
#define HD_  192
#define E_   9
#define R_   12
#define D_   64
#define B_   4
#define S_   1024
#define H3_  (3 * H_)
#define MBS_ (B_ * S_)

typedef unsigned short u16;
typedef __attribute__((ext_vector_type(4))) int   i32x4;
typedef __attribute__((ext_vector_type(4))) float f32x4;

static const long OUT_REL_OFF = (long)B_ * E_ * S_ * S_;                    // 37,748,736
static const long OUT_ENH_OFF = OUT_REL_OFF + (long)B_ * R_ * S_ * S_;      // 88,080,384

__device__ __forceinline__ u16 f2bf(float f) {
    unsigned u = __builtin_bit_cast(unsigned, f);
    return (u16)((u + 0x7fffu + ((u >> 16) & 1u)) >> 16);
}
__device__ __forceinline__ float bf2f(u16 h) {
    return __builtin_bit_cast(float, (unsigned)h << 16);
}
__device__ __forceinline__ void gload16(const u16* g, u16* l) {
    __builtin_amdgcn_global_load_lds(
        (__attribute__((address_space(1))) void*)g,
        (__attribute__((address_space(3))) void*)l, 16, 0, 0);
}
__device__ __forceinline__ void mfma_bf16(f32x4& acc, i32x4 a, i32x4 b) {
    asm volatile("v_mfma_f32_16x16x32_bf16 %0, %1, %2, %0"
                 : "+v"(acc) : "v"(a), "v"(b));
}

// ---------------------------------------------------------------------------
// bf16 MFMA GEMM, NT: C[m,n] = sum_k A[m,k]*B[n,k].
// PIPE=0: single-buffer 2-barrier drain loop (half LDS -> max residency).
// PIPE=1: 2-buffer ring with counted vmcnt.
// EPI 0: +bias (OBF sel bf16/fp32 out)
// EPI 1: logits epilogue (mask/tril/*0.125), fp32 out, float4 via LDS transpose
// EPI 3: EPI1 + per-row max partials -> aux[(z*S+gm)*16 + bx*2+wc]
// EPI 4: +bias then fused interleaved RoPE (pair via shfl_xor 1), bf16 out
// EPI 7: +bias, bf16 out, V columns (gn>=1536) also written transposed to aux
// ---------------------------------------------------------------------------
template<int BM, int BN, int EPI, int OBF, int PIPE>
__global__ __launch_bounds__(256) void gemm_mfma(
    const u16* __restrict__ A, const u16* __restrict__ Bw,
    const float* __restrict__ bias, void* __restrict__ Cv,
    int K, int lda, int ldb, int ldc, int nh,
    long sAb, long sAh, long sBb, long sBh, long sCb, long sCh,
    const float* __restrict__ mask, float scale, float* __restrict__ aux)
{
    constexpr int MI = BM / 32, NJ = BN / 32;
    constexpr int BUFE = (BM + BN) * 64;
    constexpr int LPS  = BM / 32 + BN / 32;
    const int z = blockIdx.z;
    const int zb = z / nh, zh = z - zb * nh;
    A  += zb * sAb + zh * sAh;
    Bw += zb * sBb + zh * sBh;

    const int gx = gridDim.x, gy = gridDim.y;
    int id = blockIdx.y * gx + blockIdx.x;
    const int nwg = gx * gy;
    if ((nwg & 7) == 0) id = (id & 7) * (nwg >> 3) + (id >> 3);
    const int bx = id % gx, by = id / gx;
    const int m0 = by * BM, n0 = bx * BN;

    __shared__ u16 lds[(PIPE ? 2 : 1) * BUFE];

    const int t = threadIdx.x;
    const int lane = t & 63, wid = t >> 6;
    const int wr = wid >> 1, wc = wid & 1;
    const int l16 = lane & 15, l4 = lane >> 4;

    auto stage = [&](int kt, u16* la) {
        u16* lb = la + BM * 64;
        const int k0 = kt << 6;
        #pragma unroll
        for (int i = 0; i < BM / 32; ++i) {
            const int e = i * 256 + t;
            const int row = e >> 3;
            const int c = ((e & 7) ^ (row & 7)) << 3;
            gload16(A + (long)(m0 + row) * lda + k0 + c, la + e * 8);
        }
        #pragma unroll
        for (int i = 0; i < BN / 32; ++i) {
            const int e = i * 256 + t;
            const int row = e >> 3;
            const int c = ((e & 7) ^ (row & 7)) << 3;
            gload16(Bw + (long)(n0 + row) * ldb + k0 + c, lb + e * 8);
        }
    };

    f32x4 acc[MI][NJ];
    #pragma unroll
    for (int mi = 0; mi < MI; ++mi)
        #pragma unroll
        for (int nj = 0; nj < NJ; ++nj)
            #pragma unroll
            for (int q = 0; q < 4; ++q) acc[mi][nj][q] = 0.0f;

    const int nt = K >> 6;

    if (PIPE == 0) {
        for (int tt = 0; tt < nt; ++tt) {
            stage(tt, lds);
            __syncthreads();                 // vmcnt(0) drain + barrier
            const u16* la = lds;
            const u16* lb = lds + BM * 64;
            i32x4 af[MI][2], bfr[NJ][2];
            #pragma unroll
            for (int mi = 0; mi < MI; ++mi)
                #pragma unroll
                for (int kk = 0; kk < 2; ++kk) {
                    const int row = wr * (BM / 2) + mi * 16 + l16;
                    af[mi][kk] = *(const i32x4*)&la[row * 64 + ((((kk << 2) + l4) ^ (row & 7)) << 3)];
                }
            #pragma unroll
            for (int nj = 0; nj < NJ; ++nj)
                #pragma unroll
                for (int kk = 0; kk < 2; ++kk) {
                    const int row = wc * (BN / 2) + nj * 16 + l16;
                    bfr[nj][kk] = *(const i32x4*)&lb[row * 64 + ((((kk << 2) + l4) ^ (row & 7)) << 3)];
                }
            #pragma unroll
            for (int kk = 0; kk < 2; ++kk)
                #pragma unroll
                for (int mi = 0; mi < MI; ++mi)
                    #pragma unroll
                    for (int nj = 0; nj < NJ; ++nj)
                        mfma_bf16(acc[mi][nj], af[mi][kk], bfr[nj][kk]);
            __syncthreads();                 // reads done before next stage
        }
    } else {
        stage(0, lds);
        if (nt > 1) stage(1, lds + BUFE);
        for (int tt = 0; tt < nt; ++tt) {
            if (tt + 1 < nt) {
                if constexpr (LPS == 8) asm volatile("s_waitcnt vmcnt(8)" ::: "memory");
                else if constexpr (LPS == 7) asm volatile("s_waitcnt vmcnt(7)" ::: "memory");
                else if constexpr (LPS == 6) asm volatile("s_waitcnt vmcnt(6)" ::: "memory");
                else asm volatile("s_waitcnt vmcnt(5)" ::: "memory");
            } else {
                asm volatile("s_waitcnt vmcnt(0)" ::: "memory");
            }
            __builtin_amdgcn_s_barrier();
            u16* la = lds + (tt & 1) * BUFE;
            const u16* lb = la + BM * 64;
            i32x4 af[MI][2], bfr[NJ][2];
            #pragma unroll
            for (int mi = 0; mi < MI; ++mi)
                #pragma unroll
                for (int kk = 0; kk < 2; ++kk) {
                    const int row = wr * (BM / 2) + mi * 16 + l16;
                    af[mi][kk] = *(const i32x4*)&la[row * 64 + ((((kk << 2) + l4) ^ (row & 7)) << 3)];
                }
            #pragma unroll
            for (int nj = 0; nj < NJ; ++nj)
                #pragma unroll
                for (int kk = 0; kk < 2; ++kk) {
                    const int row = wc * (BN / 2) + nj * 16 + l16;
                    bfr[nj][kk] = *(const i32x4*)&lb[row * 64 + ((((kk << 2) + l4) ^ (row & 7)) << 3)];
                }
            asm volatile("s_waitcnt lgkmcnt(0)" ::: "memory");
            __builtin_amdgcn_sched_barrier(0);
            __builtin_amdgcn_s_barrier();
            if (tt + 2 < nt) stage(tt + 2, la);
            #pragma unroll
            for (int kk = 0; kk < 2; ++kk)
                #pragma unroll
                for (int mi = 0; mi < MI; ++mi)
                    #pragma unroll
                    for (int nj = 0; nj < NJ; ++nj)
                        mfma_bf16(acc[mi][nj], af[mi][kk], bfr[nj][kk]);
        }
        __syncthreads();
    }
    __builtin_amdgcn_sched_barrier(0);
    asm volatile("s_nop 7");
    asm volatile("s_nop 7");
    __builtin_amdgcn_sched_barrier(0);

    if (EPI == 1 || EPI == 3) mask += (long)zb * S_;
    const long cbase = zb * sCb + zh * sCh;

    if constexpr (EPI == 1 || EPI == 3) {
        // logits epilogue with LDS-transposed float4 stores (BM=BN=128)
        float red[MI][4];
        if (EPI == 3) {
            #pragma unroll
            for (int mi = 0; mi < MI; ++mi)
                #pragma unroll
                for (int r = 0; r < 4; ++r) red[mi][r] = -INFINITY;
        }
        float* tl = (float*)lds;           // 32 x 132 floats = 16.9 KB
        constexpr int LDP = 132;
        #pragma unroll
        for (int c = 0; c < 4; ++c) {
            __syncthreads();
            if (wr == (c >> 1)) {
                #pragma unroll
                for (int mih = 0; mih < 2; ++mih) {
                    const int mi = (c & 1) * 2 + mih;
                    #pragma unroll
                    for (int nj = 0; nj < NJ; ++nj) {
                        const int gnl = wc * 64 + nj * 16 + l16;
                        const int gn = n0 + gnl;
                        const float pad = mask[gn];
                        #pragma unroll
                        for (int r = 0; r < 4; ++r) {
                            const int gm = m0 + wr * 64 + mi * 16 + l4 * 4 + r;
                            float v = acc[mi][nj][r];
                            v = v * pad - (1.0f - pad) * 1e12f;
                            if (gm > gn) v -= 1e12f;
                            v *= 0.125f;
                            if (EPI == 3) red[mi][r] = fmaxf(red[mi][r], v);
                            tl[(mih * 16 + l4 * 4 + r) * LDP + gnl] = v;
                        }
                    }
                }
            }
            __syncthreads();
            #pragma unroll
            for (int j = 0; j < 4; ++j) {
                const int idx = j * 256 + t;
                const int rowl = idx >> 5, f4 = idx & 31;
                const float4 vv = *(const float4*)&tl[rowl * LDP + f4 * 4];
                const int gm = m0 + c * 32 + rowl;
                *(float4*)&((float*)Cv)[cbase + (long)gm * ldc + n0 + f4 * 4] = vv;
            }
        }
        if (EPI == 3) {
            #pragma unroll
            for (int mi = 0; mi < MI; ++mi) {
                #pragma unroll
                for (int r = 0; r < 4; ++r) {
                    float m = red[mi][r];
                    m = fmaxf(m, __shfl_xor(m, 1, 64));
                    m = fmaxf(m, __shfl_xor(m, 2, 64));
                    m = fmaxf(m, __shfl_xor(m, 4, 64));
                    m = fmaxf(m, __shfl_xor(m, 8, 64));
                    if (l16 == 0) {
                        const int gm = m0 + wr * (BM / 2) + mi * 16 + l4 * 4 + r;
                        aux[((long)z * S_ + gm) * 16 + bx * 2 + wc] = m;
                    }
                }
            }
        }
    } else {
        #pragma unroll
        for (int mi = 0; mi < MI; ++mi) {
            #pragma unroll
            for (int nj = 0; nj < NJ; ++nj) {
                const int gn = n0 + wc * (BN / 2) + nj * 16 + l16;
                const float bv = (bias != nullptr) ? bias[gn] : 0.0f;
                float invf = 0.0f;
                if (EPI == 4) invf = exp2f(-(float)((gn & 63) >> 1) * 0.41524101186092503f);
                #pragma unroll
                for (int r = 0; r < 4; ++r) {
                    const int gm = m0 + wr * (BM / 2) + mi * 16 + l4 * 4 + r;
                    float v = acc[mi][nj][r];
                    const long cidx = cbase + (long)gm * ldc + gn;
                    if (EPI == 0) {
                        v += bv;
                        if (OBF) ((u16*)Cv)[cidx] = f2bf(v);
                        else     ((float*)Cv)[cidx] = v;
                    } else if (EPI == 7) {
                        v += bv;
                        const u16 bfv = f2bf(v);
                        ((u16*)Cv)[cidx] = bfv;
                        if (gn >= 2 * H_) {
                            const int hh = (gn - 2 * H_) / HD_;
                            const int dd = (gn - 2 * H_) - hh * HD_;
                            const int bb = gm >> 10, ss = gm & (S_ - 1);
                            ((u16*)aux)[((long)(bb * NH_ + hh) * HD_ + dd) * S_ + ss] = bfv;
                        }
                    } else { // EPI == 4
                        v += bv;
                        const int sp = gm & (S_ - 1);
                        float sn, cs;
                        __sincosf((float)sp * invf, &sn, &cs);
                        const float pv = __shfl_xor(v, 1, 64);
                        v = (gn & 1) ? fmaf(v, cs, pv * sn) : fmaf(v, cs, -pv * sn);
                        ((u16*)Cv)[cidx] = f2bf(v);
                    }
                }
            }
        }
    }
}

// ---------------------------------------------------------------------------
// Fused flash-style attention, QBLK=32 (512 blocks, 2/CU), setprio on MFMA.
// ---------------------------------------------------------------------------
__global__ __launch_bounds__(256) void attn_fused(
    const u16* __restrict__ qkv, const u16* __restrict__ vt,
    const float* __restrict__ mask, u16* __restrict__ ctx, float qscale)
{
    const int z = blockIdx.y;              // b*NH + h
    const int b = z >> 2, h = z & 3;
    const int s0 = blockIdx.x * 32;
    const int t = threadIdx.x;
    const int lane = t & 63, w = t >> 6;
    const int l16 = lane & 15, l4 = lane >> 4;

    __shared__ u16 k_lds[64 * 192];
    __shared__ u16 v_lds[192 * 64];
    __shared__ u16 p_lds[32 * 64];
    __shared__ float rs_lds[4][32];

    i32x4 qf[2][6];
    {
        const u16* qb = qkv + (long)(b * S_ + s0 + l16) * H3_ + h * HD_;
        #pragma unroll
        for (int mi = 0; mi < 2; ++mi)
            #pragma unroll
            for (int kk = 0; kk < 6; ++kk)
                qf[mi][kk] = *(const i32x4*)(qb + (long)mi * 16 * H3_ + kk * 32 + l4 * 8);
    }
    asm volatile("s_waitcnt vmcnt(0)" ::: "memory");

    f32x4 acc_c[2][3];
    #pragma unroll
    for (int mi = 0; mi < 2; ++mi)
        #pragma unroll
        for (int nj = 0; nj < 3; ++nj)
            #pragma unroll
            for (int q = 0; q < 4; ++q) acc_c[mi][nj][q] = 0.0f;
    float rs_acc[2][4] = {};

    const float* mrow = mask + (long)b * S_;

    for (int kt = 0; kt < 16; ++kt) {
        const int kv0 = kt * 64;
        #pragma unroll
        for (int i = 0; i < 6; ++i) {
            const int e = i * 256 + t;
            const int row = e / 24;
            const int g = e - row * 24;
            const int gs = (g & ~7) | ((g & 7) ^ (row & 7));
            gload16(qkv + (long)(b * S_ + kv0 + row) * H3_ + H_ + h * HD_ + gs * 8,
                    k_lds + e * 8);
        }
        #pragma unroll
        for (int i = 0; i < 6; ++i) {
            const int e = i * 256 + t;
            const int row = e >> 3, g = e & 7;
            const int gs = g ^ (row & 7);
            gload16(vt + ((long)z * HD_ + row) * S_ + kv0 + gs * 8,
                    v_lds + e * 8);
        }
        asm volatile("s_waitcnt vmcnt(6)" ::: "memory");
        __builtin_amdgcn_s_barrier();

        f32x4 acc_s[2];
        #pragma unroll
        for (int mi = 0; mi < 2; ++mi)
            #pragma unroll
            for (int q = 0; q < 4; ++q) acc_s[mi][q] = 0.0f;
        __builtin_amdgcn_s_setprio(1);
        #pragma unroll
        for (int kk = 0; kk < 6; ++kk) {
            const int krow = w * 16 + l16;
            const int g = kk * 4 + l4;
            const int gs = (g & ~7) | ((g & 7) ^ (krow & 7));
            const i32x4 kf = *(const i32x4*)&k_lds[krow * 192 + gs * 8];
            #pragma unroll
            for (int mi = 0; mi < 2; ++mi)
                mfma_bf16(acc_s[mi], qf[mi][kk], kf);
        }
        __builtin_amdgcn_s_setprio(0);
        __builtin_amdgcn_sched_barrier(0);
        asm volatile("s_nop 7");
        asm volatile("s_nop 7");
        __builtin_amdgcn_sched_barrier(0);

        {
            const int coll = w * 16 + l16;
            const float mk = mrow[kv0 + coll];
            #pragma unroll
            for (int mi = 0; mi < 2; ++mi) {
                #pragma unroll
                for (int r = 0; r < 4; ++r) {
                    const int rowl = mi * 16 + l4 * 4 + r;
                    float tv = 0.0f;
                    if (mk != 0.0f) tv = __expf(acc_s[mi][r] * qscale);
                    const int gs = (coll >> 3) ^ (rowl & 7);
                    p_lds[rowl * 64 + gs * 8 + (coll & 7)] = f2bf(tv);
                    float v = tv;
                    v += __shfl_xor(v, 1, 64);
                    v += __shfl_xor(v, 2, 64);
                    v += __shfl_xor(v, 4, 64);
                    v += __shfl_xor(v, 8, 64);
                    rs_acc[mi][r] += v;
                }
            }
        }

        asm volatile("s_waitcnt vmcnt(0) lgkmcnt(0)" ::: "memory");
        __builtin_amdgcn_sched_barrier(0);
        __builtin_amdgcn_s_barrier();

        __builtin_amdgcn_s_setprio(1);
        #pragma unroll
        for (int kk = 0; kk < 2; ++kk) {
            i32x4 pf[2];
            #pragma unroll
            for (int mi = 0; mi < 2; ++mi) {
                const int row = mi * 16 + l16;
                const int gs = (kk * 4 + l4) ^ (row & 7);
                pf[mi] = *(const i32x4*)&p_lds[row * 64 + gs * 8];
            }
            #pragma unroll
            for (int nj = 0; nj < 3; ++nj) {
                const int row = w * 48 + nj * 16 + l16;
                const int gs = (kk * 4 + l4) ^ (row & 7);
                const i32x4 vf = *(const i32x4*)&v_lds[row * 64 + gs * 8];
                #pragma unroll
                for (int mi = 0; mi < 2; ++mi)
                    mfma_bf16(acc_c[mi][nj], pf[mi], vf);
            }
        }
        __builtin_amdgcn_s_setprio(0);
        __builtin_amdgcn_s_barrier();
    }

    __builtin_amdgcn_sched_barrier(0);
    asm volatile("s_nop 7");
    asm volatile("s_nop 7");
    __builtin_amdgcn_sched_barrier(0);

    if (l16 == 0) {
        #pragma unroll
        for (int mi = 0; mi < 2; ++mi)
            #pragma unroll
            for (int r = 0; r < 4; ++r)
                rs_lds[w][mi * 16 + l4 * 4 + r] = rs_acc[mi][r];
    }
    __syncthreads();

    #pragma unroll
    for (int mi = 0; mi < 2; ++mi) {
        #pragma unroll
        for (int r = 0; r < 4; ++r) {
            const int rowl = mi * 16 + l4 * 4 + r;
            const float inv = 1.0f / (rs_lds[0][rowl] + rs_lds[1][rowl] +
                                      rs_lds[2][rowl] + rs_lds[3][rowl]);
            #pragma unroll
            for (int nj = 0; nj < 3; ++nj) {
                const int d = w * 48 + nj * 16 + l16;
                ctx[(long)(b * S_ + s0 + rowl) * H_ + h * HD_ + d] =
                    f2bf(acc_c[mi][nj][r] * inv);
            }
        }
    }
}

// ---------------------------------------------------------------------------
// Fused fp32->bf16 cast of hs + 5 weight matrices + bias2 concat.
// ---------------------------------------------------------------------------
__global__ __launch_bounds__(256) void cast_all(
    const float* __restrict__ hs, const float* __restrict__ ipw,
    const float* __restrict__ opw, const float* __restrict__ gw,
    const float* __restrict__ entw, const float* __restrict__ relw,
    const float* __restrict__ opb, const float* __restrict__ gb,
    u16* hs_o, u16* ipw_o, u16* opw_o, u16* gw_o, u16* entw_o, u16* relw_o,
    float* bias2)
{
    const int blk = blockIdx.x;
    if (blk >= 9120) {
        const float* src = (blk == 9120) ? opb : gb;
        float* dst = bias2 + (blk - 9120) * H_;
        if (threadIdx.x < 192)
            *(float4*)&dst[threadIdx.x * 4] = *(const float4*)&src[threadIdx.x * 4];
        return;
    }
    const float* in; u16* out; long base;
    if      (blk < 3072) { in = hs;   out = hs_o;   base = (long)blk * 1024; }
    else if (blk < 4800) { in = ipw;  out = ipw_o;  base = (long)(blk - 3072) * 1024; }
    else if (blk < 5376) { in = opw;  out = opw_o;  base = (long)(blk - 4800) * 1024; }
    else if (blk < 5952) { in = gw;   out = gw_o;   base = (long)(blk - 5376) * 1024; }
    else if (blk < 6816) { in = entw; out = entw_o; base = (long)(blk - 5952) * 1024; }
    else                 { in = relw; out = relw_o; base = (long)(blk - 6816) * 1024; }
    const long idx = base + (long)threadIdx.x * 4;
    const float4 v = *(const float4*)&in[idx];
    ushort4 o; o.x = f2bf(v.x); o.y = f2bf(v.y); o.z = f2bf(v.z); o.w = f2bf(v.w);
    *(ushort4*)&out[idx] = o;
}

// ---------------------------------------------------------------------------
// x = hs + sigmoid(gl)*ao ; LayerNorm -> enh fp32 (d_out) + relh[:768] bf16
// ---------------------------------------------------------------------------
__global__ __launch_bounds__(256) void gate_ln_bf(
    const float* __restrict__ hs, const u16* __restrict__ aogl,
    const float* __restrict__ g, const float* __restrict__ bta,
    float* __restrict__ enh, u16* __restrict__ relh)
{
    const long row = blockIdx.x;
    const float* hrow = hs + row * H_;
    const u16* arow = aogl + row * (2 * H_);
    const int tid = threadIdx.x;
    float x[3];
    float sum = 0.0f, sq = 0.0f;
    #pragma unroll
    for (int i = 0; i < 3; ++i) {
        const int j = tid + i * 256;
        const float a = bf2f(arow[j]);
        const float gt = 1.0f / (1.0f + __expf(-bf2f(arow[H_ + j])));
        const float xv = hrow[j] + gt * a;
        x[i] = xv; sum += xv; sq += xv * xv;
    }
    __shared__ float sm[8];
    #pragma unroll
    for (int o = 32; o > 0; o >>= 1) {
        sum += __shfl_xor(sum, o, 64);
        sq  += __shfl_xor(sq, o, 64);
    }
    const int lane = tid & 63, wid = tid >> 6;
    if (lane == 0) { sm[wid] = sum; sm[4 + wid] = sq; }
    __syncthreads();
    sum = sm[0] + sm[1] + sm[2] + sm[3];
    sq  = sm[4] + sm[5] + sm[6] + sm[7];
    const float mu = sum * (1.0f / (float)H_);
    float var = sq * (1.0f / (float)H_) - mu * mu;
    var = fmaxf(var, 0.0f);
    const float inv = 1.0f / sqrtf(var + 1e-5f);
    #pragma unroll
    for (int i = 0; i < 3; ++i) {
        const int j = tid + i * 256;
        const float o = (x[i] - mu) * inv * g[j] + bta[j];
        enh[row * H_ + j] = o;
        relh[row * (2 * H_) + j] = f2bf(o);
    }
}

// ---------------------------------------------------------------------------
// Fused: prior[t] = max over 16 partials; relh[:,768:] = relu(prior@pw^T+pb)
// ---------------------------------------------------------------------------
__global__ __launch_bounds__(256) void prior_fused(
    const float* __restrict__ pmax, const float* __restrict__ pw,
    const float* __restrict__ pb, u16* __restrict__ relh)
{
    const int row = blockIdx.x;               // b*S + m
    const int b = row >> 10, m = row & (S_ - 1);
    __shared__ float pr[E_];
    const int tid = threadIdx.x;
    if (tid < E_) {
        const float* pp = pmax + ((long)(b * E_ + tid) * S_ + m) * 16;
        float mx = -INFINITY;
        #pragma unroll
        for (int i = 0; i < 16; ++i) mx = fmaxf(mx, pp[i]);
        pr[tid] = mx;
    }
    __syncthreads();
    float p[E_];
    #pragma unroll
    for (int e = 0; e < E_; ++e) p[e] = pr[e];
    u16* orow = relh + (long)row * (2 * H_) + H_;
    #pragma unroll
    for (int i = 0; i < 3; ++i) {
        const int j = tid + i * 256;
        float a = pb[j];
        #pragma unroll
        for (int e = 0; e < E_; ++e) a = fmaf(p[e], pw[j * E_ + e], a);
        orow[j] = f2bf(fmaxf(a, 0.0f));
    }
}

// ---------------------------------------------------------------------------
extern "C" void kernel_launch(void* const* d_in, const int* in_sizes, int n_in,
                              void* d_out, int out_size, void* d_ws, size_t ws_size,
                              hipStream_t stream)
{
    const float* hs   = (const float*)d_in[0];
    const float* mask = (const float*)d_in[1];
    const float* ipw  = (const float*)d_in[2];
    const float* ipb  = (const float*)d_in[3];
    const float* opw  = (const float*)d_in[4];
    const float* opb  = (const float*)d_in[5];
    const float* gw   = (const float*)d_in[6];
    const float* gb   = (const float*)d_in[7];
    const float* lng  = (const float*)d_in[8];
    const float* lnb  = (const float*)d_in[9];
    const float* entw = (const float*)d_in[10];
    const float* entb = (const float*)d_in[11];
    const float* prw  = (const float*)d_in[12];
    const float* prb  = (const float*)d_in[13];
    const float* relw = (const float*)d_in[14];
    const float* relb = (const float*)d_in[15];
    float* out = (float*)d_out;
    char* base = (char*)d_ws;

    // ws layout (bytes)
    u16* ipw_bf  = (u16*)(base + 0);          // 3,538,944
    u16* opw_bf  = (u16*)(base + 3538944);    // 1,179,648  } contiguous pair ->
    u16* gw_bf   = (u16*)(base + 4718592);    // 1,179,648  } combined [1536][768]
    u16* entw_bf = (u16*)(base + 5898240);    // 1,769,472
    u16* relw_bf = (u16*)(base + 7667712);    // 4,718,592
    u16* hs_bf   = (u16*)(base + 12386304);   // 6,291,456
    u16* qkv_bf  = (u16*)(base + 18677760);   // 18,874,368 [dead after attn]
    u16* vt_bf   = (u16*)(base + 37552128);   // 6,291,456  [dead after attn]
    u16* ctx_bf  = (u16*)(base + 77398016);   // 6,291,456
    u16* aogl_bf = (u16*)(base + 83689472);   // 12,582,912
    float* bias2 = (float*)(base + 96272384); //      6,144 (opb|gb)
    float* pmax  = (float*)(base + 97329152); //  2,359,296
    u16* relh_bf = (u16*)(base + 43843584);   // 12,582,912
    u16* projr   = (u16*)(base + 56426496);   // 12,582,912
    float* enh   = out + OUT_ENH_OFF;

    const float qscale = 0.07216878364870323f; // 1/sqrt(192)

    // 0. casts (+ bias2 concat in blocks 9120/9121)
    cast_all<<<9122, 256, 0, stream>>>(hs, ipw, opw, gw, entw, relw, opb, gb,
                                       hs_bf, ipw_bf, opw_bf, gw_bf, entw_bf, relw_bf,
                                       bias2);

    // 1. qkv = hs @ in_proj_w.T + b (4096 x 2304, K=768) + fused V-transpose
    //    single-buffer drain loop: 28 KB LDS -> 3 blocks/CU (grid exactly 3/CU)
    gemm_mfma<128,96,7,1,0><<<dim3(24, 32, 1), 256, 0, stream>>>(
        hs_bf, ipw_bf, ipb, qkv_bf, H_, H_, H_, H3_, 1,
        0,0,0,0,0,0, nullptr, 0.0f, (float*)vt_bf);

    // 2. fused attention: ctx = softmax(QK^T) @ V   (512 blocks, 2/CU)
    attn_fused<<<dim3(32, 16), 256, 0, stream>>>(
        qkv_bf, vt_bf, mask, ctx_bf, qscale);

    // 3. [attn_out | gate_lin] = ctx @ [opw|gw]^T + [opb|gb]  (4096 x 1536, K=768)
    gemm_mfma<128,96,0,1,1><<<dim3(16, 32, 1), 256, 0, stream>>>(
        ctx_bf, opw_bf, bias2, aogl_bf, H_, H_, H_, 2 * H_, 1,
        0,0,0,0,0,0, nullptr, 0.0f, nullptr);

    // 4. enhanced = LN(hs + sigmoid(gl)*ao) -> enh fp32 + relh[:768]
    gate_ln_bf<<<MBS_, 256, 0, stream>>>(hs, aogl_bf, lng, lnb, enh, relh_bf);

    // 5. ent projection + fused RoPE (4096 x 1152, K=768) -> projr bf16
    gemm_mfma<64,96,4,1,1><<<dim3(12, 64, 1), 256, 0, stream>>>(
        relh_bf, entw_bf, entb, projr, H_, 2 * H_, H_, E_ * 2 * D_, 1,
        0,0,0,0,0,0, nullptr, 0.0f, nullptr);

    // 6. ent logits + fused rowmax partials -> out[0], pmax   (K=64)
    gemm_mfma<128,128,3,0,0><<<dim3(8, 8, B_ * E_), 256, 0, stream>>>(
        projr, projr + D_, nullptr, out, D_, E_ * 2 * D_, E_ * 2 * D_, S_, E_,
        (long)S_ * E_ * 2 * D_, 2 * D_, (long)S_ * E_ * 2 * D_, 2 * D_,
        (long)E_ * S_ * S_, (long)S_ * S_, mask, 0.0f, pmax);

    // 7. prior reduce + feat -> relh[:, 768:]
    prior_fused<<<MBS_, 256, 0, stream>>>(pmax, prw, prb, relh_bf);

    // 8. rel projection + fused RoPE (4096 x 1536, K=1536) -> projr bf16
    gemm_mfma<128,96,4,1,1><<<dim3(16, 32, 1), 256, 0, stream>>>(
        relh_bf, relw_bf, relb, projr, 2 * H_, 2 * H_, 2 * H_, R_ * 2 * D_, 1,
        0,0,0,0,0,0, nullptr, 0.0f, nullptr);

    // 9. rel logits -> out[1]   (48 x 1024 x 1024, K=64)
    gemm_mfma<128,128,1,0,0><<<dim3(8, 8, B_ * R_), 256, 0, stream>>>(
        projr, projr + D_, nullptr, out + OUT_REL_OFF, D_, R_ * 2 * D_, R_ * 2 * D_, S_, R_,
        (long)S_ * R_ * 2 * D_, 2 * D_, (long)S_ * R_ * 2 * D_, 2 * D_,
        (long)R_ * S_ * S_, (long)S_ * S_, mask, 0.0f, nullptr);

    (void)in_sizes; (void)n_in; (void)out_size; (void)ws_size;
}

// Round 11
// 240.416 us; speedup vs baseline: 1.0714x; 1.0210x over previous
//
#include <hip/hip_runtime.h>
#include <math.h>

#define H_   768
#define NH_  4
#define HD_  192
#define E_   9
#define R_   12
#define D_   64
#define B_   4
#define S_   1024
#define H3_  (3 * H_)
#define MBS_ (B_ * S_)

typedef unsigned short u16;
typedef __attribute__((ext_vector_type(4))) int   i32x4;
typedef __attribute__((ext_vector_type(4))) float f32x4;

static const long OUT_REL_OFF = (long)B_ * E_ * S_ * S_;                    // 37,748,736
static const long OUT_ENH_OFF = OUT_REL_OFF + (long)B_ * R_ * S_ * S_;      // 88,080,384

__device__ __forceinline__ u16 f2bf(float f) {
    unsigned u = __builtin_bit_cast(unsigned, f);
    return (u16)((u + 0x7fffu + ((u >> 16) & 1u)) >> 16);
}
__device__ __forceinline__ float bf2f(u16 h) {
    return __builtin_bit_cast(float, (unsigned)h << 16);
}
__device__ __forceinline__ void gload16(const u16* g, u16* l) {
    __builtin_amdgcn_global_load_lds(
        (__attribute__((address_space(1))) void*)g,
        (__attribute__((address_space(3))) void*)l, 16, 0, 0);
}
__device__ __forceinline__ void mfma_bf16(f32x4& acc, i32x4 a, i32x4 b) {
    asm volatile("v_mfma_f32_16x16x32_bf16 %0, %1, %2, %0"
                 : "+v"(acc) : "v"(a), "v"(b));
}

// ---------------------------------------------------------------------------
// bf16 MFMA GEMM, NT: C[m,n] = sum_k A[m,k]*B[n,k].
// PIPE=0: single-buffer drain loop. PIPE=1: 2-buffer counted-vmcnt ring.
// EPI 0: +bias (OBF sel bf16/fp32 out)
// EPI 1: logits epilogue (mask/tril/*0.125), fp32 out, float4 via LDS
//        transpose; fully-below-diagonal tiles take a constant-write fast path
// EPI 3: EPI1 + per-row max partials -> aux[(z*S+gm)*16 + bx*2+wc]
// EPI 4: +bias then fused interleaved RoPE (pair via shfl_xor 1), bf16 out
// EPI 7: +bias, bf16 out, V columns (gn>=1536) also written transposed to aux
// ---------------------------------------------------------------------------
template<int BM, int BN, int EPI, int OBF, int PIPE>
__global__ __launch_bounds__(256) void gemm_mfma(
    const u16* __restrict__ A, const u16* __restrict__ Bw,
    const float* __restrict__ bias, void* __restrict__ Cv,
    int K, int lda, int ldb, int ldc, int nh,
    long sAb, long sAh, long sBb, long sBh, long sCb, long sCh,
    const float* __restrict__ mask, float scale, float* __restrict__ aux)
{
    constexpr int MI = BM / 32, NJ = BN / 32;
    constexpr int BUFE = (BM + BN) * 64;
    constexpr int LPS  = BM / 32 + BN / 32;
    const int z = blockIdx.z;
    const int zb = z / nh, zh = z - zb * nh;
    A  += zb * sAb + zh * sAh;
    Bw += zb * sBb + zh * sBh;

    const int gx = gridDim.x, gy = gridDim.y;
    int id = blockIdx.y * gx + blockIdx.x;
    const int nwg = gx * gy;
    if ((nwg & 7) == 0) id = (id & 7) * (nwg >> 3) + (id >> 3);
    const int bx = id % gx, by = id / gx;
    const int m0 = by * BM, n0 = bx * BN;

    const int t = threadIdx.x;

    if constexpr (EPI == 1 || EPI == 3) {
        // Causal fast path: tile entirely below diagonal -> constant output.
        // True value = qk/8 - 1.25e11 (pad=1) with |qk/8| << 2.5e9 threshold.
        if (m0 >= n0 + BN) {
            const long cb2 = (long)zb * sCb + (long)zh * sCh;
            const float* mrow2 = mask + (long)zb * S_;
            if (EPI == 3) {
                const int row = t >> 1, slot = t & 1;
                aux[((long)z * S_ + m0 + row) * 16 + bx * 2 + slot] = -1e30f;
            }
            #pragma unroll
            for (int j = 0; j < (BM * BN) / 1024; ++j) {
                const int idx = j * 256 + t;
                const int row = idx / (BN / 4), f4 = idx % (BN / 4);
                float4 vv;
                float* pv = (float*)&vv;
                #pragma unroll
                for (int k2 = 0; k2 < 4; ++k2) {
                    const float pad = mrow2[n0 + f4 * 4 + k2];
                    pv[k2] = (pad != 0.0f) ? -1.25e11f : -2.5e11f;
                }
                *(float4*)&((float*)Cv)[cb2 + (long)(m0 + row) * ldc + n0 + f4 * 4] = vv;
            }
            return;
        }
    }

    __shared__ u16 lds[(PIPE ? 2 : 1) * BUFE];

    const int lane = t & 63, wid = t >> 6;
    const int wr = wid >> 1, wc = wid & 1;
    const int l16 = lane & 15, l4 = lane >> 4;

    auto stage = [&](int kt, u16* la) {
        u16* lb = la + BM * 64;
        const int k0 = kt << 6;
        #pragma unroll
        for (int i = 0; i < BM / 32; ++i) {
            const int e = i * 256 + t;
            const int row = e >> 3;
            const int c = ((e & 7) ^ (row & 7)) << 3;
            gload16(A + (long)(m0 + row) * lda + k0 + c, la + e * 8);
        }
        #pragma unroll
        for (int i = 0; i < BN / 32; ++i) {
            const int e = i * 256 + t;
            const int row = e >> 3;
            const int c = ((e & 7) ^ (row & 7)) << 3;
            gload16(Bw + (long)(n0 + row) * ldb + k0 + c, lb + e * 8);
        }
    };

    f32x4 acc[MI][NJ];
    #pragma unroll
    for (int mi = 0; mi < MI; ++mi)
        #pragma unroll
        for (int nj = 0; nj < NJ; ++nj)
            #pragma unroll
            for (int q = 0; q < 4; ++q) acc[mi][nj][q] = 0.0f;

    const int nt = K >> 6;

    if (PIPE == 0) {
        for (int tt = 0; tt < nt; ++tt) {
            stage(tt, lds);
            __syncthreads();                 // vmcnt(0) drain + barrier
            const u16* la = lds;
            const u16* lb = lds + BM * 64;
            i32x4 af[MI][2], bfr[NJ][2];
            #pragma unroll
            for (int mi = 0; mi < MI; ++mi)
                #pragma unroll
                for (int kk = 0; kk < 2; ++kk) {
                    const int row = wr * (BM / 2) + mi * 16 + l16;
                    af[mi][kk] = *(const i32x4*)&la[row * 64 + ((((kk << 2) + l4) ^ (row & 7)) << 3)];
                }
            #pragma unroll
            for (int nj = 0; nj < NJ; ++nj)
                #pragma unroll
                for (int kk = 0; kk < 2; ++kk) {
                    const int row = wc * (BN / 2) + nj * 16 + l16;
                    bfr[nj][kk] = *(const i32x4*)&lb[row * 64 + ((((kk << 2) + l4) ^ (row & 7)) << 3)];
                }
            #pragma unroll
            for (int kk = 0; kk < 2; ++kk)
                #pragma unroll
                for (int mi = 0; mi < MI; ++mi)
                    #pragma unroll
                    for (int nj = 0; nj < NJ; ++nj)
                        mfma_bf16(acc[mi][nj], af[mi][kk], bfr[nj][kk]);
            __syncthreads();                 // reads done before next stage
        }
    } else {
        stage(0, lds);
        if (nt > 1) stage(1, lds + BUFE);
        for (int tt = 0; tt < nt; ++tt) {
            if (tt + 1 < nt) {
                if constexpr (LPS == 8) asm volatile("s_waitcnt vmcnt(8)" ::: "memory");
                else if constexpr (LPS == 7) asm volatile("s_waitcnt vmcnt(7)" ::: "memory");
                else if constexpr (LPS == 6) asm volatile("s_waitcnt vmcnt(6)" ::: "memory");
                else asm volatile("s_waitcnt vmcnt(5)" ::: "memory");
            } else {
                asm volatile("s_waitcnt vmcnt(0)" ::: "memory");
            }
            __builtin_amdgcn_s_barrier();
            u16* la = lds + (tt & 1) * BUFE;
            const u16* lb = la + BM * 64;
            i32x4 af[MI][2], bfr[NJ][2];
            #pragma unroll
            for (int mi = 0; mi < MI; ++mi)
                #pragma unroll
                for (int kk = 0; kk < 2; ++kk) {
                    const int row = wr * (BM / 2) + mi * 16 + l16;
                    af[mi][kk] = *(const i32x4*)&la[row * 64 + ((((kk << 2) + l4) ^ (row & 7)) << 3)];
                }
            #pragma unroll
            for (int nj = 0; nj < NJ; ++nj)
                #pragma unroll
                for (int kk = 0; kk < 2; ++kk) {
                    const int row = wc * (BN / 2) + nj * 16 + l16;
                    bfr[nj][kk] = *(const i32x4*)&lb[row * 64 + ((((kk << 2) + l4) ^ (row & 7)) << 3)];
                }
            asm volatile("s_waitcnt lgkmcnt(0)" ::: "memory");
            __builtin_amdgcn_sched_barrier(0);
            __builtin_amdgcn_s_barrier();
            if (tt + 2 < nt) stage(tt + 2, la);
            #pragma unroll
            for (int kk = 0; kk < 2; ++kk)
                #pragma unroll
                for (int mi = 0; mi < MI; ++mi)
                    #pragma unroll
                    for (int nj = 0; nj < NJ; ++nj)
                        mfma_bf16(acc[mi][nj], af[mi][kk], bfr[nj][kk]);
        }
        __syncthreads();
    }
    __builtin_amdgcn_sched_barrier(0);
    asm volatile("s_nop 7");
    asm volatile("s_nop 7");
    __builtin_amdgcn_sched_barrier(0);

    if (EPI == 1 || EPI == 3) mask += (long)zb * S_;
    const long cbase = zb * sCb + zh * sCh;

    if constexpr (EPI == 1 || EPI == 3) {
        // logits epilogue with LDS-transposed float4 stores (BM=BN=128)
        float red[MI][4];
        if (EPI == 3) {
            #pragma unroll
            for (int mi = 0; mi < MI; ++mi)
                #pragma unroll
                for (int r = 0; r < 4; ++r) red[mi][r] = -INFINITY;
        }
        float* tl = (float*)lds;           // 32 x 132 floats = 16.9 KB
        constexpr int LDP = 132;
        #pragma unroll
        for (int c = 0; c < 4; ++c) {
            __syncthreads();
            if (wr == (c >> 1)) {
                #pragma unroll
                for (int mih = 0; mih < 2; ++mih) {
                    const int mi = (c & 1) * 2 + mih;
                    #pragma unroll
                    for (int nj = 0; nj < NJ; ++nj) {
                        const int gnl = wc * 64 + nj * 16 + l16;
                        const int gn = n0 + gnl;
                        const float pad = mask[gn];
                        #pragma unroll
                        for (int r = 0; r < 4; ++r) {
                            const int gm = m0 + wr * 64 + mi * 16 + l4 * 4 + r;
                            float v = acc[mi][nj][r];
                            v = v * pad - (1.0f - pad) * 1e12f;
                            if (gm > gn) v -= 1e12f;
                            v *= 0.125f;
                            if (EPI == 3) red[mi][r] = fmaxf(red[mi][r], v);
                            tl[(mih * 16 + l4 * 4 + r) * LDP + gnl] = v;
                        }
                    }
                }
            }
            __syncthreads();
            #pragma unroll
            for (int j = 0; j < 4; ++j) {
                const int idx = j * 256 + t;
                const int rowl = idx >> 5, f4 = idx & 31;
                const float4 vv = *(const float4*)&tl[rowl * LDP + f4 * 4];
                const int gm = m0 + c * 32 + rowl;
                *(float4*)&((float*)Cv)[cbase + (long)gm * ldc + n0 + f4 * 4] = vv;
            }
        }
        if (EPI == 3) {
            #pragma unroll
            for (int mi = 0; mi < MI; ++mi) {
                #pragma unroll
                for (int r = 0; r < 4; ++r) {
                    float m = red[mi][r];
                    m = fmaxf(m, __shfl_xor(m, 1, 64));
                    m = fmaxf(m, __shfl_xor(m, 2, 64));
                    m = fmaxf(m, __shfl_xor(m, 4, 64));
                    m = fmaxf(m, __shfl_xor(m, 8, 64));
                    if (l16 == 0) {
                        const int gm = m0 + wr * (BM / 2) + mi * 16 + l4 * 4 + r;
                        aux[((long)z * S_ + gm) * 16 + bx * 2 + wc] = m;
                    }
                }
            }
        }
    } else {
        #pragma unroll
        for (int mi = 0; mi < MI; ++mi) {
            #pragma unroll
            for (int nj = 0; nj < NJ; ++nj) {
                const int gn = n0 + wc * (BN / 2) + nj * 16 + l16;
                const float bv = (bias != nullptr) ? bias[gn] : 0.0f;
                float invf = 0.0f;
                if (EPI == 4) invf = exp2f(-(float)((gn & 63) >> 1) * 0.41524101186092503f);
                #pragma unroll
                for (int r = 0; r < 4; ++r) {
                    const int gm = m0 + wr * (BM / 2) + mi * 16 + l4 * 4 + r;
                    float v = acc[mi][nj][r];
                    const long cidx = cbase + (long)gm * ldc + gn;
                    if (EPI == 0) {
                        v += bv;
                        if (OBF) ((u16*)Cv)[cidx] = f2bf(v);
                        else     ((float*)Cv)[cidx] = v;
                    } else if (EPI == 7) {
                        v += bv;
                        const u16 bfv = f2bf(v);
                        ((u16*)Cv)[cidx] = bfv;
                        if (gn >= 2 * H_) {
                            const int hh = (gn - 2 * H_) / HD_;
                            const int dd = (gn - 2 * H_) - hh * HD_;
                            const int bb = gm >> 10, ss = gm & (S_ - 1);
                            ((u16*)aux)[((long)(bb * NH_ + hh) * HD_ + dd) * S_ + ss] = bfv;
                        }
                    } else { // EPI == 4
                        v += bv;
                        const int sp = gm & (S_ - 1);
                        float sn, cs;
                        __sincosf((float)sp * invf, &sn, &cs);
                        const float pv = __shfl_xor(v, 1, 64);
                        v = (gn & 1) ? fmaf(v, cs, pv * sn) : fmaf(v, cs, -pv * sn);
                        ((u16*)Cv)[cidx] = f2bf(v);
                    }
                }
            }
        }
    }
}

// ---------------------------------------------------------------------------
// Fused flash-style attention, QBLK=32 (512 blocks, 2/CU), setprio on MFMA.
// ---------------------------------------------------------------------------
__global__ __launch_bounds__(256) void attn_fused(
    const u16* __restrict__ qkv, const u16* __restrict__ vt,
    const float* __restrict__ mask, u16* __restrict__ ctx, float qscale)
{
    const int z = blockIdx.y;              // b*NH + h
    const int b = z >> 2, h = z & 3;
    const int s0 = blockIdx.x * 32;
    const int t = threadIdx.x;
    const int lane = t & 63, w = t >> 6;
    const int l16 = lane & 15, l4 = lane >> 4;

    __shared__ u16 k_lds[64 * 192];
    __shared__ u16 v_lds[192 * 64];
    __shared__ u16 p_lds[32 * 64];
    __shared__ float rs_lds[4][32];

    i32x4 qf[2][6];
    {
        const u16* qb = qkv + (long)(b * S_ + s0 + l16) * H3_ + h * HD_;
        #pragma unroll
        for (int mi = 0; mi < 2; ++mi)
            #pragma unroll
            for (int kk = 0; kk < 6; ++kk)
                qf[mi][kk] = *(const i32x4*)(qb + (long)mi * 16 * H3_ + kk * 32 + l4 * 8);
    }
    asm volatile("s_waitcnt vmcnt(0)" ::: "memory");

    f32x4 acc_c[2][3];
    #pragma unroll
    for (int mi = 0; mi < 2; ++mi)
        #pragma unroll
        for (int nj = 0; nj < 3; ++nj)
            #pragma unroll
            for (int q = 0; q < 4; ++q) acc_c[mi][nj][q] = 0.0f;
    float rs_acc[2][4] = {};

    const float* mrow = mask + (long)b * S_;

    for (int kt = 0; kt < 16; ++kt) {
        const int kv0 = kt * 64;
        #pragma unroll
        for (int i = 0; i < 6; ++i) {
            const int e = i * 256 + t;
            const int row = e / 24;
            const int g = e - row * 24;
            const int gs = (g & ~7) | ((g & 7) ^ (row & 7));
            gload16(qkv + (long)(b * S_ + kv0 + row) * H3_ + H_ + h * HD_ + gs * 8,
                    k_lds + e * 8);
        }
        #pragma unroll
        for (int i = 0; i < 6; ++i) {
            const int e = i * 256 + t;
            const int row = e >> 3, g = e & 7;
            const int gs = g ^ (row & 7);
            gload16(vt + ((long)z * HD_ + row) * S_ + kv0 + gs * 8,
                    v_lds + e * 8);
        }
        asm volatile("s_waitcnt vmcnt(6)" ::: "memory");
        __builtin_amdgcn_s_barrier();

        f32x4 acc_s[2];
        #pragma unroll
        for (int mi = 0; mi < 2; ++mi)
            #pragma unroll
            for (int q = 0; q < 4; ++q) acc_s[mi][q] = 0.0f;
        __builtin_amdgcn_s_setprio(1);
        #pragma unroll
        for (int kk = 0; kk < 6; ++kk) {
            const int krow = w * 16 + l16;
            const int g = kk * 4 + l4;
            const int gs = (g & ~7) | ((g & 7) ^ (krow & 7));
            const i32x4 kf = *(const i32x4*)&k_lds[krow * 192 + gs * 8];
            #pragma unroll
            for (int mi = 0; mi < 2; ++mi)
                mfma_bf16(acc_s[mi], qf[mi][kk], kf);
        }
        __builtin_amdgcn_s_setprio(0);
        __builtin_amdgcn_sched_barrier(0);
        asm volatile("s_nop 7");
        asm volatile("s_nop 7");
        __builtin_amdgcn_sched_barrier(0);

        {
            const int coll = w * 16 + l16;
            const float mk = mrow[kv0 + coll];
            #pragma unroll
            for (int mi = 0; mi < 2; ++mi) {
                #pragma unroll
                for (int r = 0; r < 4; ++r) {
                    const int rowl = mi * 16 + l4 * 4 + r;
                    float tv = 0.0f;
                    if (mk != 0.0f) tv = __expf(acc_s[mi][r] * qscale);
                    const int gs = (coll >> 3) ^ (rowl & 7);
                    p_lds[rowl * 64 + gs * 8 + (coll & 7)] = f2bf(tv);
                    float v = tv;
                    v += __shfl_xor(v, 1, 64);
                    v += __shfl_xor(v, 2, 64);
                    v += __shfl_xor(v, 4, 64);
                    v += __shfl_xor(v, 8, 64);
                    rs_acc[mi][r] += v;
                }
            }
        }

        asm volatile("s_waitcnt vmcnt(0) lgkmcnt(0)" ::: "memory");
        __builtin_amdgcn_sched_barrier(0);
        __builtin_amdgcn_s_barrier();

        __builtin_amdgcn_s_setprio(1);
        #pragma unroll
        for (int kk = 0; kk < 2; ++kk) {
            i32x4 pf[2];
            #pragma unroll
            for (int mi = 0; mi < 2; ++mi) {
                const int row = mi * 16 + l16;
                const int gs = (kk * 4 + l4) ^ (row & 7);
                pf[mi] = *(const i32x4*)&p_lds[row * 64 + gs * 8];
            }
            #pragma unroll
            for (int nj = 0; nj < 3; ++nj) {
                const int row = w * 48 + nj * 16 + l16;
                const int gs = (kk * 4 + l4) ^ (row & 7);
                const i32x4 vf = *(const i32x4*)&v_lds[row * 64 + gs * 8];
                #pragma unroll
                for (int mi = 0; mi < 2; ++mi)
                    mfma_bf16(acc_c[mi][nj], pf[mi], vf);
            }
        }
        __builtin_amdgcn_s_setprio(0);
        __builtin_amdgcn_s_barrier();
    }

    __builtin_amdgcn_sched_barrier(0);
    asm volatile("s_nop 7");
    asm volatile("s_nop 7");
    __builtin_amdgcn_sched_barrier(0);

    if (l16 == 0) {
        #pragma unroll
        for (int mi = 0; mi < 2; ++mi)
            #pragma unroll
            for (int r = 0; r < 4; ++r)
                rs_lds[w][mi * 16 + l4 * 4 + r] = rs_acc[mi][r];
    }
    __syncthreads();

    #pragma unroll
    for (int mi = 0; mi < 2; ++mi) {
        #pragma unroll
        for (int r = 0; r < 4; ++r) {
            const int rowl = mi * 16 + l4 * 4 + r;
            const float inv = 1.0f / (rs_lds[0][rowl] + rs_lds[1][rowl] +
                                      rs_lds[2][rowl] + rs_lds[3][rowl]);
            #pragma unroll
            for (int nj = 0; nj < 3; ++nj) {
                const int d = w * 48 + nj * 16 + l16;
                ctx[(long)(b * S_ + s0 + rowl) * H_ + h * HD_ + d] =
                    f2bf(acc_c[mi][nj][r] * inv);
            }
        }
    }
}

// ---------------------------------------------------------------------------
// Fused fp32->bf16 cast of hs + 5 weight matrices + bias2 concat.
// ---------------------------------------------------------------------------
__global__ __launch_bounds__(256) void cast_all(
    const float* __restrict__ hs, const float* __restrict__ ipw,
    const float* __restrict__ opw, const float* __restrict__ gw,
    const float* __restrict__ entw, const float* __restrict__ relw,
    const float* __restrict__ opb, const float* __restrict__ gb,
    u16* hs_o, u16* ipw_o, u16* opw_o, u16* gw_o, u16* entw_o, u16* relw_o,
    float* bias2)
{
    const int blk = blockIdx.x;
    if (blk >= 9120) {
        const float* src = (blk == 9120) ? opb : gb;
        float* dst = bias2 + (blk - 9120) * H_;
        if (threadIdx.x < 192)
            *(float4*)&dst[threadIdx.x * 4] = *(const float4*)&src[threadIdx.x * 4];
        return;
    }
    const float* in; u16* out; long base;
    if      (blk < 3072) { in = hs;   out = hs_o;   base = (long)blk * 1024; }
    else if (blk < 4800) { in = ipw;  out = ipw_o;  base = (long)(blk - 3072) * 1024; }
    else if (blk < 5376) { in = opw;  out = opw_o;  base = (long)(blk - 4800) * 1024; }
    else if (blk < 5952) { in = gw;   out = gw_o;   base = (long)(blk - 5376) * 1024; }
    else if (blk < 6816) { in = entw; out = entw_o; base = (long)(blk - 5952) * 1024; }
    else                 { in = relw; out = relw_o; base = (long)(blk - 6816) * 1024; }
    const long idx = base + (long)threadIdx.x * 4;
    const float4 v = *(const float4*)&in[idx];
    ushort4 o; o.x = f2bf(v.x); o.y = f2bf(v.y); o.z = f2bf(v.z); o.w = f2bf(v.w);
    *(ushort4*)&out[idx] = o;
}

// ---------------------------------------------------------------------------
// x = hs + sigmoid(gl)*ao ; LayerNorm -> enh fp32 (d_out) + relh[:768] bf16
// ---------------------------------------------------------------------------
__global__ __launch_bounds__(256) void gate_ln_bf(
    const float* __restrict__ hs, const u16* __restrict__ aogl,
    const float* __restrict__ g, const float* __restrict__ bta,
    float* __restrict__ enh, u16* __restrict__ relh)
{
    const long row = blockIdx.x;
    const float* hrow = hs + row * H_;
    const u16* arow = aogl + row * (2 * H_);
    const int tid = threadIdx.x;
    float x[3];
    float sum = 0.0f, sq = 0.0f;
    #pragma unroll
    for (int i = 0; i < 3; ++i) {
        const int j = tid + i * 256;
        const float a = bf2f(arow[j]);
        const float gt = 1.0f / (1.0f + __expf(-bf2f(arow[H_ + j])));
        const float xv = hrow[j] + gt * a;
        x[i] = xv; sum += xv; sq += xv * xv;
    }
    __shared__ float sm[8];
    #pragma unroll
    for (int o = 32; o > 0; o >>= 1) {
        sum += __shfl_xor(sum, o, 64);
        sq  += __shfl_xor(sq, o, 64);
    }
    const int lane = tid & 63, wid = tid >> 6;
    if (lane == 0) { sm[wid] = sum; sm[4 + wid] = sq; }
    __syncthreads();
    sum = sm[0] + sm[1] + sm[2] + sm[3];
    sq  = sm[4] + sm[5] + sm[6] + sm[7];
    const float mu = sum * (1.0f / (float)H_);
    float var = sq * (1.0f / (float)H_) - mu * mu;
    var = fmaxf(var, 0.0f);
    const float inv = 1.0f / sqrtf(var + 1e-5f);
    #pragma unroll
    for (int i = 0; i < 3; ++i) {
        const int j = tid + i * 256;
        const float o = (x[i] - mu) * inv * g[j] + bta[j];
        enh[row * H_ + j] = o;
        relh[row * (2 * H_) + j] = f2bf(o);
    }
}

// ---------------------------------------------------------------------------
// Fused: prior[t] = max over 16 partials; relh[:,768:] = relu(prior@pw^T+pb)
// ---------------------------------------------------------------------------
__global__ __launch_bounds__(256) void prior_fused(
    const float* __restrict__ pmax, const float* __restrict__ pw,
    const float* __restrict__ pb, u16* __restrict__ relh)
{
    const int row = blockIdx.x;               // b*S + m
    const int b = row >> 10, m = row & (S_ - 1);
    __shared__ float pr[E_];
    const int tid = threadIdx.x;
    if (tid < E_) {
        const float* pp = pmax + ((long)(b * E_ + tid) * S_ + m) * 16;
        float mx = -INFINITY;
        #pragma unroll
        for (int i = 0; i < 16; ++i) mx = fmaxf(mx, pp[i]);
        pr[tid] = mx;
    }
    __syncthreads();
    float p[E_];
    #pragma unroll
    for (int e = 0; e < E_; ++e) p[e] = pr[e];
    u16* orow = relh + (long)row * (2 * H_) + H_;
    #pragma unroll
    for (int i = 0; i < 3; ++i) {
        const int j = tid + i * 256;
        float a = pb[j];
        #pragma unroll
        for (int e = 0; e < E_; ++e) a = fmaf(p[e], pw[j * E_ + e], a);
        orow[j] = f2bf(fmaxf(a, 0.0f));
    }
}

// ---------------------------------------------------------------------------
extern "C" void kernel_launch(void* const* d_in, const int* in_sizes, int n_in,
                              void* d_out, int out_size, void* d_ws, size_t ws_size,
                              hipStream_t stream)
{
    const float* hs   = (const float*)d_in[0];
    const float* mask = (const float*)d_in[1];
    const float* ipw  = (const float*)d_in[2];
    const float* ipb  = (const float*)d_in[3];
    const float* opw  = (const float*)d_in[4];
    const float* opb  = (const float*)d_in[5];
    const float* gw   = (const float*)d_in[6];
    const float* gb   = (const float*)d_in[7];
    const float* lng  = (const float*)d_in[8];
    const float* lnb  = (const float*)d_in[9];
    const float* entw = (const float*)d_in[10];
    const float* entb = (const float*)d_in[11];
    const float* prw  = (const float*)d_in[12];
    const float* prb  = (const float*)d_in[13];
    const float* relw = (const float*)d_in[14];
    const float* relb = (const float*)d_in[15];
    float* out = (float*)d_out;
    char* base = (char*)d_ws;

    // ws layout (bytes)
    u16* ipw_bf  = (u16*)(base + 0);          // 3,538,944
    u16* opw_bf  = (u16*)(base + 3538944);    // 1,179,648  } contiguous pair ->
    u16* gw_bf   = (u16*)(base + 4718592);    // 1,179,648  } combined [1536][768]
    u16* entw_bf = (u16*)(base + 5898240);    // 1,769,472
    u16* relw_bf = (u16*)(base + 7667712);    // 4,718,592
    u16* hs_bf   = (u16*)(base + 12386304);   // 6,291,456
    u16* qkv_bf  = (u16*)(base + 18677760);   // 18,874,368 [dead after attn]
    u16* vt_bf   = (u16*)(base + 37552128);   // 6,291,456  [dead after attn]
    u16* ctx_bf  = (u16*)(base + 77398016);   // 6,291,456
    u16* aogl_bf = (u16*)(base + 83689472);   // 12,582,912
    float* bias2 = (float*)(base + 96272384); //      6,144 (opb|gb)
    float* pmax  = (float*)(base + 97329152); //  2,359,296
    u16* relh_bf = (u16*)(base + 43843584);   // 12,582,912
    u16* projr   = (u16*)(base + 56426496);   // 12,582,912
    float* enh   = out + OUT_ENH_OFF;

    const float qscale = 0.07216878364870323f; // 1/sqrt(192)

    // 0. casts (+ bias2 concat in blocks 9120/9121)
    cast_all<<<9122, 256, 0, stream>>>(hs, ipw, opw, gw, entw, relw, opb, gb,
                                       hs_bf, ipw_bf, opw_bf, gw_bf, entw_bf, relw_bf,
                                       bias2);

    // 1. qkv = hs @ in_proj_w.T + b (4096 x 2304, K=768) + fused V-transpose
    gemm_mfma<128,96,7,1,0><<<dim3(24, 32, 1), 256, 0, stream>>>(
        hs_bf, ipw_bf, ipb, qkv_bf, H_, H_, H_, H3_, 1,
        0,0,0,0,0,0, nullptr, 0.0f, (float*)vt_bf);

    // 2. fused attention: ctx = softmax(QK^T) @ V   (512 blocks, 2/CU)
    attn_fused<<<dim3(32, 16), 256, 0, stream>>>(
        qkv_bf, vt_bf, mask, ctx_bf, qscale);

    // 3. [attn_out | gate_lin] = ctx @ [opw|gw]^T + [opb|gb]  (4096 x 1536, K=768)
    gemm_mfma<128,96,0,1,1><<<dim3(16, 32, 1), 256, 0, stream>>>(
        ctx_bf, opw_bf, bias2, aogl_bf, H_, H_, H_, 2 * H_, 1,
        0,0,0,0,0,0, nullptr, 0.0f, nullptr);

    // 4. enhanced = LN(hs + sigmoid(gl)*ao) -> enh fp32 + relh[:768]
    gate_ln_bf<<<MBS_, 256, 0, stream>>>(hs, aogl_bf, lng, lnb, enh, relh_bf);

    // 5. ent projection + fused RoPE (4096 x 1152, K=768) -> projr bf16
    gemm_mfma<64,96,4,1,1><<<dim3(12, 64, 1), 256, 0, stream>>>(
        relh_bf, entw_bf, entb, projr, H_, 2 * H_, H_, E_ * 2 * D_, 1,
        0,0,0,0,0,0, nullptr, 0.0f, nullptr);

    // 6. ent logits + fused rowmax partials -> out[0], pmax   (K=64)
    gemm_mfma<128,128,3,0,0><<<dim3(8, 8, B_ * E_), 256, 0, stream>>>(
        projr, projr + D_, nullptr, out, D_, E_ * 2 * D_, E_ * 2 * D_, S_, E_,
        (long)S_ * E_ * 2 * D_, 2 * D_, (long)S_ * E_ * 2 * D_, 2 * D_,
        (long)E_ * S_ * S_, (long)S_ * S_, mask, 0.0f, pmax);

    // 7. prior reduce + feat -> relh[:, 768:]
    prior_fused<<<MBS_, 256, 0, stream>>>(pmax, prw, prb, relh_bf);

    // 8. rel projection + fused RoPE (4096 x 1536, K=1536) -> projr bf16
    gemm_mfma<128,96,4,1,1><<<dim3(16, 32, 1), 256, 0, stream>>>(
        relh_bf, relw_bf, relb, projr, 2 * H_, 2 * H_, 2 * H_, R_ * 2 * D_, 1,
        0,0,0,0,0,0, nullptr, 0.0f, nullptr);

    // 9. rel logits -> out[1]   (48 x 1024 x 1024, K=64)
    gemm_mfma<128,128,1,0,0><<<dim3(8, 8, B_ * R_), 256, 0, stream>>>(
        projr, projr + D_, nullptr, out + OUT_REL_OFF, D_, R_ * 2 * D_, R_ * 2 * D_, S_, R_,
        (long)S_ * R_ * 2 * D_, 2 * D_, (long)S_ * R_ * 2 * D_, 2 * D_,
        (long)R_ * S_ * S_, (long)S_ * S_, mask, 0.0f, nullptr);

    (void)in_sizes; (void)n_in; (void)out_size; (void)ws_size;
}

// Round 12
// 230.411 us; speedup vs baseline: 1.1179x; 1.0434x over previous
//
#include <hip/hip_runtime.h>
#include <math.h>

#define H_   768
#define NH_  4
#define HD_  192
#define E_   9
#define R_   12
#define D_   64
#define B_   4
#define S_   1024
#define H3_  (3 * H_)
#define MBS_ (B_ * S_)

typedef unsigned short u16;
typedef __attribute__((ext_vector_type(4))) int   i32x4;
typedef __attribute__((ext_vector_type(4))) float f32x4;

static const long OUT_REL_OFF = (long)B_ * E_ * S_ * S_;                    // 37,748,736
static const long OUT_ENH_OFF = OUT_REL_OFF + (long)B_ * R_ * S_ * S_;      // 88,080,384

__device__ __forceinline__ u16 f2bf(float f) {
    unsigned u = __builtin_bit_cast(unsigned, f);
    return (u16)((u + 0x7fffu + ((u >> 16) & 1u)) >> 16);
}
__device__ __forceinline__ float bf2f(u16 h) {
    return __builtin_bit_cast(float, (unsigned)h << 16);
}
__device__ __forceinline__ void gload16(const u16* g, u16* l) {
    __builtin_amdgcn_global_load_lds(
        (__attribute__((address_space(1))) void*)g,
        (__attribute__((address_space(3))) void*)l, 16, 0, 0);
}
__device__ __forceinline__ void mfma_bf16(f32x4& acc, i32x4 a, i32x4 b) {
    asm volatile("v_mfma_f32_16x16x32_bf16 %0, %1, %2, %0"
                 : "+v"(acc) : "v"(a), "v"(b));
}
__device__ __forceinline__ void nt_store4(float* p, f32x4 v) {
    __builtin_nontemporal_store(v, (f32x4*)p);
}

// ---------------------------------------------------------------------------
// bf16 MFMA GEMM, NT: C[m,n] = sum_k A[m,k]*B[n,k].
// PIPE=0: single-buffer drain loop. PIPE=1: 2-buffer counted-vmcnt ring.
// EPI 0: +bias (OBF sel bf16/fp32 out)
// EPI 1: logits epilogue (mask/tril/*0.125), fp32 nontemporal out via LDS
//        transpose; fully-below-diagonal tiles take a constant-write fast path
// EPI 3: EPI1 + per-row max partials -> aux[(z*S+gm)*16 + bx*2+wc]
// EPI 4: +bias then fused interleaved RoPE (pair via shfl_xor 1), bf16 out
// EPI 7: +bias, bf16 out, V columns (gn>=1536) also written transposed to aux
// ---------------------------------------------------------------------------
template<int BM, int BN, int EPI, int OBF, int PIPE>
__global__ __launch_bounds__(256) void gemm_mfma(
    const u16* __restrict__ A, const u16* __restrict__ Bw,
    const float* __restrict__ bias, void* __restrict__ Cv,
    int K, int lda, int ldb, int ldc, int nh,
    long sAb, long sAh, long sBb, long sBh, long sCb, long sCh,
    const float* __restrict__ mask, float scale, float* __restrict__ aux)
{
    constexpr int MI = BM / 32, NJ = BN / 32;
    constexpr int BUFE = (BM + BN) * 64;
    constexpr int LPS  = BM / 32 + BN / 32;
    const int z = blockIdx.z;
    const int zb = z / nh, zh = z - zb * nh;
    A  += zb * sAb + zh * sAh;
    Bw += zb * sBb + zh * sBh;

    const int gx = gridDim.x, gy = gridDim.y;
    int id = blockIdx.y * gx + blockIdx.x;
    const int nwg = gx * gy;
    if ((nwg & 7) == 0) id = (id & 7) * (nwg >> 3) + (id >> 3);
    const int bx = id % gx, by = id / gx;
    const int m0 = by * BM, n0 = bx * BN;

    const int t = threadIdx.x;

    if constexpr (EPI == 1 || EPI == 3) {
        // Causal fast path: tile entirely below diagonal -> constant output.
        if (m0 >= n0 + BN) {
            const long cb2 = (long)zb * sCb + (long)zh * sCh;
            const float* mrow2 = mask + (long)zb * S_;
            if (EPI == 3) {
                const int row = t >> 1, slot = t & 1;
                aux[((long)z * S_ + m0 + row) * 16 + bx * 2 + slot] = -1e30f;
            }
            #pragma unroll
            for (int j = 0; j < (BM * BN) / 1024; ++j) {
                const int idx = j * 256 + t;
                const int row = idx / (BN / 4), f4 = idx % (BN / 4);
                f32x4 vv;
                #pragma unroll
                for (int k2 = 0; k2 < 4; ++k2) {
                    const float pad = mrow2[n0 + f4 * 4 + k2];
                    vv[k2] = (pad != 0.0f) ? -1.25e11f : -2.5e11f;
                }
                nt_store4(&((float*)Cv)[cb2 + (long)(m0 + row) * ldc + n0 + f4 * 4], vv);
            }
            return;
        }
    }

    __shared__ u16 lds[(PIPE ? 2 : 1) * BUFE];

    const int lane = t & 63, wid = t >> 6;
    const int wr = wid >> 1, wc = wid & 1;
    const int l16 = lane & 15, l4 = lane >> 4;

    auto stage = [&](int kt, u16* la) {
        u16* lb = la + BM * 64;
        const int k0 = kt << 6;
        #pragma unroll
        for (int i = 0; i < BM / 32; ++i) {
            const int e = i * 256 + t;
            const int row = e >> 3;
            const int c = ((e & 7) ^ (row & 7)) << 3;
            gload16(A + (long)(m0 + row) * lda + k0 + c, la + e * 8);
        }
        #pragma unroll
        for (int i = 0; i < BN / 32; ++i) {
            const int e = i * 256 + t;
            const int row = e >> 3;
            const int c = ((e & 7) ^ (row & 7)) << 3;
            gload16(Bw + (long)(n0 + row) * ldb + k0 + c, lb + e * 8);
        }
    };

    f32x4 acc[MI][NJ];
    #pragma unroll
    for (int mi = 0; mi < MI; ++mi)
        #pragma unroll
        for (int nj = 0; nj < NJ; ++nj)
            #pragma unroll
            for (int q = 0; q < 4; ++q) acc[mi][nj][q] = 0.0f;

    const int nt = K >> 6;

    if (PIPE == 0) {
        for (int tt = 0; tt < nt; ++tt) {
            stage(tt, lds);
            __syncthreads();
            const u16* la = lds;
            const u16* lb = lds + BM * 64;
            i32x4 af[MI][2], bfr[NJ][2];
            #pragma unroll
            for (int mi = 0; mi < MI; ++mi)
                #pragma unroll
                for (int kk = 0; kk < 2; ++kk) {
                    const int row = wr * (BM / 2) + mi * 16 + l16;
                    af[mi][kk] = *(const i32x4*)&la[row * 64 + ((((kk << 2) + l4) ^ (row & 7)) << 3)];
                }
            #pragma unroll
            for (int nj = 0; nj < NJ; ++nj)
                #pragma unroll
                for (int kk = 0; kk < 2; ++kk) {
                    const int row = wc * (BN / 2) + nj * 16 + l16;
                    bfr[nj][kk] = *(const i32x4*)&lb[row * 64 + ((((kk << 2) + l4) ^ (row & 7)) << 3)];
                }
            #pragma unroll
            for (int kk = 0; kk < 2; ++kk)
                #pragma unroll
                for (int mi = 0; mi < MI; ++mi)
                    #pragma unroll
                    for (int nj = 0; nj < NJ; ++nj)
                        mfma_bf16(acc[mi][nj], af[mi][kk], bfr[nj][kk]);
            __syncthreads();
        }
    } else {
        stage(0, lds);
        if (nt > 1) stage(1, lds + BUFE);
        for (int tt = 0; tt < nt; ++tt) {
            if (tt + 1 < nt) {
                if constexpr (LPS == 8) asm volatile("s_waitcnt vmcnt(8)" ::: "memory");
                else if constexpr (LPS == 7) asm volatile("s_waitcnt vmcnt(7)" ::: "memory");
                else if constexpr (LPS == 6) asm volatile("s_waitcnt vmcnt(6)" ::: "memory");
                else asm volatile("s_waitcnt vmcnt(5)" ::: "memory");
            } else {
                asm volatile("s_waitcnt vmcnt(0)" ::: "memory");
            }
            __builtin_amdgcn_s_barrier();
            u16* la = lds + (tt & 1) * BUFE;
            const u16* lb = la + BM * 64;
            i32x4 af[MI][2], bfr[NJ][2];
            #pragma unroll
            for (int mi = 0; mi < MI; ++mi)
                #pragma unroll
                for (int kk = 0; kk < 2; ++kk) {
                    const int row = wr * (BM / 2) + mi * 16 + l16;
                    af[mi][kk] = *(const i32x4*)&la[row * 64 + ((((kk << 2) + l4) ^ (row & 7)) << 3)];
                }
            #pragma unroll
            for (int nj = 0; nj < NJ; ++nj)
                #pragma unroll
                for (int kk = 0; kk < 2; ++kk) {
                    const int row = wc * (BN / 2) + nj * 16 + l16;
                    bfr[nj][kk] = *(const i32x4*)&lb[row * 64 + ((((kk << 2) + l4) ^ (row & 7)) << 3)];
                }
            asm volatile("s_waitcnt lgkmcnt(0)" ::: "memory");
            __builtin_amdgcn_sched_barrier(0);
            __builtin_amdgcn_s_barrier();
            if (tt + 2 < nt) stage(tt + 2, la);
            #pragma unroll
            for (int kk = 0; kk < 2; ++kk)
                #pragma unroll
                for (int mi = 0; mi < MI; ++mi)
                    #pragma unroll
                    for (int nj = 0; nj < NJ; ++nj)
                        mfma_bf16(acc[mi][nj], af[mi][kk], bfr[nj][kk]);
        }
        __syncthreads();
    }
    __builtin_amdgcn_sched_barrier(0);
    asm volatile("s_nop 7");
    asm volatile("s_nop 7");
    __builtin_amdgcn_sched_barrier(0);

    if (EPI == 1 || EPI == 3) mask += (long)zb * S_;
    const long cbase = zb * sCb + zh * sCh;

    if constexpr (EPI == 1 || EPI == 3) {
        float red[MI][4];
        if (EPI == 3) {
            #pragma unroll
            for (int mi = 0; mi < MI; ++mi)
                #pragma unroll
                for (int r = 0; r < 4; ++r) red[mi][r] = -INFINITY;
        }
        float* tl = (float*)lds;           // 32 x 132 floats
        constexpr int LDP = 132;
        #pragma unroll
        for (int c = 0; c < 4; ++c) {
            __syncthreads();
            if (wr == (c >> 1)) {
                #pragma unroll
                for (int mih = 0; mih < 2; ++mih) {
                    const int mi = (c & 1) * 2 + mih;
                    #pragma unroll
                    for (int nj = 0; nj < NJ; ++nj) {
                        const int gnl = wc * 64 + nj * 16 + l16;
                        const int gn = n0 + gnl;
                        const float pad = mask[gn];
                        #pragma unroll
                        for (int r = 0; r < 4; ++r) {
                            const int gm = m0 + wr * 64 + mi * 16 + l4 * 4 + r;
                            float v = acc[mi][nj][r];
                            v = v * pad - (1.0f - pad) * 1e12f;
                            if (gm > gn) v -= 1e12f;
                            v *= 0.125f;
                            if (EPI == 3) red[mi][r] = fmaxf(red[mi][r], v);
                            tl[(mih * 16 + l4 * 4 + r) * LDP + gnl] = v;
                        }
                    }
                }
            }
            __syncthreads();
            #pragma unroll
            for (int j = 0; j < 4; ++j) {
                const int idx = j * 256 + t;
                const int rowl = idx >> 5, f4 = idx & 31;
                const f32x4 vv = *(const f32x4*)&tl[rowl * LDP + f4 * 4];
                const int gm = m0 + c * 32 + rowl;
                nt_store4(&((float*)Cv)[cbase + (long)gm * ldc + n0 + f4 * 4], vv);
            }
        }
        if (EPI == 3) {
            #pragma unroll
            for (int mi = 0; mi < MI; ++mi) {
                #pragma unroll
                for (int r = 0; r < 4; ++r) {
                    float m = red[mi][r];
                    m = fmaxf(m, __shfl_xor(m, 1, 64));
                    m = fmaxf(m, __shfl_xor(m, 2, 64));
                    m = fmaxf(m, __shfl_xor(m, 4, 64));
                    m = fmaxf(m, __shfl_xor(m, 8, 64));
                    if (l16 == 0) {
                        const int gm = m0 + wr * (BM / 2) + mi * 16 + l4 * 4 + r;
                        aux[((long)z * S_ + gm) * 16 + bx * 2 + wc] = m;
                    }
                }
            }
        }
    } else {
        #pragma unroll
        for (int mi = 0; mi < MI; ++mi) {
            #pragma unroll
            for (int nj = 0; nj < NJ; ++nj) {
                const int gn = n0 + wc * (BN / 2) + nj * 16 + l16;
                const float bv = (bias != nullptr) ? bias[gn] : 0.0f;
                float invf = 0.0f;
                if (EPI == 4) invf = exp2f(-(float)((gn & 63) >> 1) * 0.41524101186092503f);
                #pragma unroll
                for (int r = 0; r < 4; ++r) {
                    const int gm = m0 + wr * (BM / 2) + mi * 16 + l4 * 4 + r;
                    float v = acc[mi][nj][r];
                    const long cidx = cbase + (long)gm * ldc + gn;
                    if (EPI == 0) {
                        v += bv;
                        if (OBF) ((u16*)Cv)[cidx] = f2bf(v);
                        else     ((float*)Cv)[cidx] = v;
                    } else if (EPI == 7) {
                        v += bv;
                        const u16 bfv = f2bf(v);
                        ((u16*)Cv)[cidx] = bfv;
                        if (gn >= 2 * H_) {
                            const int hh = (gn - 2 * H_) / HD_;
                            const int dd = (gn - 2 * H_) - hh * HD_;
                            const int bb = gm >> 10, ss = gm & (S_ - 1);
                            ((u16*)aux)[((long)(bb * NH_ + hh) * HD_ + dd) * S_ + ss] = bfv;
                        }
                    } else { // EPI == 4
                        v += bv;
                        const int sp = gm & (S_ - 1);
                        float sn, cs;
                        __sincosf((float)sp * invf, &sn, &cs);
                        const float pv = __shfl_xor(v, 1, 64);
                        v = (gn & 1) ? fmaf(v, cs, pv * sn) : fmaf(v, cs, -pv * sn);
                        ((u16*)Cv)[cidx] = f2bf(v);
                    }
                }
            }
        }
    }
}

// ---------------------------------------------------------------------------
// Fused flash-style attention, QBLK=32. XCD-pinned z: linear id -> z=id&15,
// q-tile=id>>4, so (under dispatch%8 -> XCD) each XCD owns z in {k, k+8}
// exclusively -> KV panels stay in one L2.
// ---------------------------------------------------------------------------
__global__ __launch_bounds__(256) void attn_fused(
    const u16* __restrict__ qkv, const u16* __restrict__ vt,
    const float* __restrict__ mask, u16* __restrict__ ctx, float qscale)
{
    const int linear = blockIdx.y * gridDim.x + blockIdx.x;
    const int z = linear & 15;             // b*NH + h
    const int b = z >> 2, h = z & 3;
    const int s0 = (linear >> 4) * 32;
    const int t = threadIdx.x;
    const int lane = t & 63, w = t >> 6;
    const int l16 = lane & 15, l4 = lane >> 4;

    __shared__ u16 k_lds[64 * 192];
    __shared__ u16 v_lds[192 * 64];
    __shared__ u16 p_lds[32 * 64];
    __shared__ float rs_lds[4][32];

    i32x4 qf[2][6];
    {
        const u16* qb = qkv + (long)(b * S_ + s0 + l16) * H3_ + h * HD_;
        #pragma unroll
        for (int mi = 0; mi < 2; ++mi)
            #pragma unroll
            for (int kk = 0; kk < 6; ++kk)
                qf[mi][kk] = *(const i32x4*)(qb + (long)mi * 16 * H3_ + kk * 32 + l4 * 8);
    }
    asm volatile("s_waitcnt vmcnt(0)" ::: "memory");

    f32x4 acc_c[2][3];
    #pragma unroll
    for (int mi = 0; mi < 2; ++mi)
        #pragma unroll
        for (int nj = 0; nj < 3; ++nj)
            #pragma unroll
            for (int q = 0; q < 4; ++q) acc_c[mi][nj][q] = 0.0f;
    float rs_acc[2][4] = {};

    const float* mrow = mask + (long)b * S_;

    for (int kt = 0; kt < 16; ++kt) {
        const int kv0 = kt * 64;
        #pragma unroll
        for (int i = 0; i < 6; ++i) {
            const int e = i * 256 + t;
            const int row = e / 24;
            const int g = e - row * 24;
            const int gs = (g & ~7) | ((g & 7) ^ (row & 7));
            gload16(qkv + (long)(b * S_ + kv0 + row) * H3_ + H_ + h * HD_ + gs * 8,
                    k_lds + e * 8);
        }
        #pragma unroll
        for (int i = 0; i < 6; ++i) {
            const int e = i * 256 + t;
            const int row = e >> 3, g = e & 7;
            const int gs = g ^ (row & 7);
            gload16(vt + ((long)z * HD_ + row) * S_ + kv0 + gs * 8,
                    v_lds + e * 8);
        }
        asm volatile("s_waitcnt vmcnt(6)" ::: "memory");
        __builtin_amdgcn_s_barrier();

        f32x4 acc_s[2];
        #pragma unroll
        for (int mi = 0; mi < 2; ++mi)
            #pragma unroll
            for (int q = 0; q < 4; ++q) acc_s[mi][q] = 0.0f;
        __builtin_amdgcn_s_setprio(1);
        #pragma unroll
        for (int kk = 0; kk < 6; ++kk) {
            const int krow = w * 16 + l16;
            const int g = kk * 4 + l4;
            const int gs = (g & ~7) | ((g & 7) ^ (krow & 7));
            const i32x4 kf = *(const i32x4*)&k_lds[krow * 192 + gs * 8];
            #pragma unroll
            for (int mi = 0; mi < 2; ++mi)
                mfma_bf16(acc_s[mi], qf[mi][kk], kf);
        }
        __builtin_amdgcn_s_setprio(0);
        __builtin_amdgcn_sched_barrier(0);
        asm volatile("s_nop 7");
        asm volatile("s_nop 7");
        __builtin_amdgcn_sched_barrier(0);

        {
            const int coll = w * 16 + l16;
            const float mk = mrow[kv0 + coll];
            #pragma unroll
            for (int mi = 0; mi < 2; ++mi) {
                #pragma unroll
                for (int r = 0; r < 4; ++r) {
                    const int rowl = mi * 16 + l4 * 4 + r;
                    float tv = 0.0f;
                    if (mk != 0.0f) tv = __expf(acc_s[mi][r] * qscale);
                    const int gs = (coll >> 3) ^ (rowl & 7);
                    p_lds[rowl * 64 + gs * 8 + (coll & 7)] = f2bf(tv);
                    float v = tv;
                    v += __shfl_xor(v, 1, 64);
                    v += __shfl_xor(v, 2, 64);
                    v += __shfl_xor(v, 4, 64);
                    v += __shfl_xor(v, 8, 64);
                    rs_acc[mi][r] += v;
                }
            }
        }

        asm volatile("s_waitcnt vmcnt(0) lgkmcnt(0)" ::: "memory");
        __builtin_amdgcn_sched_barrier(0);
        __builtin_amdgcn_s_barrier();

        __builtin_amdgcn_s_setprio(1);
        #pragma unroll
        for (int kk = 0; kk < 2; ++kk) {
            i32x4 pf[2];
            #pragma unroll
            for (int mi = 0; mi < 2; ++mi) {
                const int row = mi * 16 + l16;
                const int gs = (kk * 4 + l4) ^ (row & 7);
                pf[mi] = *(const i32x4*)&p_lds[row * 64 + gs * 8];
            }
            #pragma unroll
            for (int nj = 0; nj < 3; ++nj) {
                const int row = w * 48 + nj * 16 + l16;
                const int gs = (kk * 4 + l4) ^ (row & 7);
                const i32x4 vf = *(const i32x4*)&v_lds[row * 64 + gs * 8];
                #pragma unroll
                for (int mi = 0; mi < 2; ++mi)
                    mfma_bf16(acc_c[mi][nj], pf[mi], vf);
            }
        }
        __builtin_amdgcn_s_setprio(0);
        __builtin_amdgcn_s_barrier();
    }

    __builtin_amdgcn_sched_barrier(0);
    asm volatile("s_nop 7");
    asm volatile("s_nop 7");
    __builtin_amdgcn_sched_barrier(0);

    if (l16 == 0) {
        #pragma unroll
        for (int mi = 0; mi < 2; ++mi)
            #pragma unroll
            for (int r = 0; r < 4; ++r)
                rs_lds[w][mi * 16 + l4 * 4 + r] = rs_acc[mi][r];
    }
    __syncthreads();

    #pragma unroll
    for (int mi = 0; mi < 2; ++mi) {
        #pragma unroll
        for (int r = 0; r < 4; ++r) {
            const int rowl = mi * 16 + l4 * 4 + r;
            const float inv = 1.0f / (rs_lds[0][rowl] + rs_lds[1][rowl] +
                                      rs_lds[2][rowl] + rs_lds[3][rowl]);
            #pragma unroll
            for (int nj = 0; nj < 3; ++nj) {
                const int d = w * 48 + nj * 16 + l16;
                ctx[(long)(b * S_ + s0 + rowl) * H_ + h * HD_ + d] =
                    f2bf(acc_c[mi][nj][r] * inv);
            }
        }
    }
}

// ---------------------------------------------------------------------------
// Fused fp32->bf16 cast of hs + 5 weight matrices + bias2 concat.
// ---------------------------------------------------------------------------
__global__ __launch_bounds__(256) void cast_all(
    const float* __restrict__ hs, const float* __restrict__ ipw,
    const float* __restrict__ opw, const float* __restrict__ gw,
    const float* __restrict__ entw, const float* __restrict__ relw,
    const float* __restrict__ opb, const float* __restrict__ gb,
    u16* hs_o, u16* ipw_o, u16* opw_o, u16* gw_o, u16* entw_o, u16* relw_o,
    float* bias2)
{
    const int blk = blockIdx.x;
    if (blk >= 9120) {
        const float* src = (blk == 9120) ? opb : gb;
        float* dst = bias2 + (blk - 9120) * H_;
        if (threadIdx.x < 192)
            *(float4*)&dst[threadIdx.x * 4] = *(const float4*)&src[threadIdx.x * 4];
        return;
    }
    const float* in; u16* out; long base;
    if      (blk < 3072) { in = hs;   out = hs_o;   base = (long)blk * 1024; }
    else if (blk < 4800) { in = ipw;  out = ipw_o;  base = (long)(blk - 3072) * 1024; }
    else if (blk < 5376) { in = opw;  out = opw_o;  base = (long)(blk - 4800) * 1024; }
    else if (blk < 5952) { in = gw;   out = gw_o;   base = (long)(blk - 5376) * 1024; }
    else if (blk < 6816) { in = entw; out = entw_o; base = (long)(blk - 5952) * 1024; }
    else                 { in = relw; out = relw_o; base = (long)(blk - 6816) * 1024; }
    const long idx = base + (long)threadIdx.x * 4;
    const float4 v = *(const float4*)&in[idx];
    ushort4 o; o.x = f2bf(v.x); o.y = f2bf(v.y); o.z = f2bf(v.z); o.w = f2bf(v.w);
    *(ushort4*)&out[idx] = o;
}

// ---------------------------------------------------------------------------
// x = hs + sigmoid(gl)*ao ; LayerNorm -> enh fp32 (d_out) + relh[:768] bf16
// ---------------------------------------------------------------------------
__global__ __launch_bounds__(256) void gate_ln_bf(
    const float* __restrict__ hs, const u16* __restrict__ aogl,
    const float* __restrict__ g, const float* __restrict__ bta,
    float* __restrict__ enh, u16* __restrict__ relh)
{
    const long row = blockIdx.x;
    const float* hrow = hs + row * H_;
    const u16* arow = aogl + row * (2 * H_);
    const int tid = threadIdx.x;
    float x[3];
    float sum = 0.0f, sq = 0.0f;
    #pragma unroll
    for (int i = 0; i < 3; ++i) {
        const int j = tid + i * 256;
        const float a = bf2f(arow[j]);
        const float gt = 1.0f / (1.0f + __expf(-bf2f(arow[H_ + j])));
        const float xv = hrow[j] + gt * a;
        x[i] = xv; sum += xv; sq += xv * xv;
    }
    __shared__ float sm[8];
    #pragma unroll
    for (int o = 32; o > 0; o >>= 1) {
        sum += __shfl_xor(sum, o, 64);
        sq  += __shfl_xor(sq, o, 64);
    }
    const int lane = tid & 63, wid = tid >> 6;
    if (lane == 0) { sm[wid] = sum; sm[4 + wid] = sq; }
    __syncthreads();
    sum = sm[0] + sm[1] + sm[2] + sm[3];
    sq  = sm[4] + sm[5] + sm[6] + sm[7];
    const float mu = sum * (1.0f / (float)H_);
    float var = sq * (1.0f / (float)H_) - mu * mu;
    var = fmaxf(var, 0.0f);
    const float inv = 1.0f / sqrtf(var + 1e-5f);
    #pragma unroll
    for (int i = 0; i < 3; ++i) {
        const int j = tid + i * 256;
        const float o = (x[i] - mu) * inv * g[j] + bta[j];
        enh[row * H_ + j] = o;
        relh[row * (2 * H_) + j] = f2bf(o);
    }
}

// ---------------------------------------------------------------------------
// Fused: prior[t] = max over 16 partials; relh[:,768:] = relu(prior@pw^T+pb)
// ---------------------------------------------------------------------------
__global__ __launch_bounds__(256) void prior_fused(
    const float* __restrict__ pmax, const float* __restrict__ pw,
    const float* __restrict__ pb, u16* __restrict__ relh)
{
    const int row = blockIdx.x;               // b*S + m
    const int b = row >> 10, m = row & (S_ - 1);
    __shared__ float pr[E_];
    const int tid = threadIdx.x;
    if (tid < E_) {
        const float* pp = pmax + ((long)(b * E_ + tid) * S_ + m) * 16;
        float mx = -INFINITY;
        #pragma unroll
        for (int i = 0; i < 16; ++i) mx = fmaxf(mx, pp[i]);
        pr[tid] = mx;
    }
    __syncthreads();
    float p[E_];
    #pragma unroll
    for (int e = 0; e < E_; ++e) p[e] = pr[e];
    u16* orow = relh + (long)row * (2 * H_) + H_;
    #pragma unroll
    for (int i = 0; i < 3; ++i) {
        const int j = tid + i * 256;
        float a = pb[j];
        #pragma unroll
        for (int e = 0; e < E_; ++e) a = fmaf(p[e], pw[j * E_ + e], a);
        orow[j] = f2bf(fmaxf(a, 0.0f));
    }
}

// ---------------------------------------------------------------------------
extern "C" void kernel_launch(void* const* d_in, const int* in_sizes, int n_in,
                              void* d_out, int out_size, void* d_ws, size_t ws_size,
                              hipStream_t stream)
{
    const float* hs   = (const float*)d_in[0];
    const float* mask = (const float*)d_in[1];
    const float* ipw  = (const float*)d_in[2];
    const float* ipb  = (const float*)d_in[3];
    const float* opw  = (const float*)d_in[4];
    const float* opb  = (const float*)d_in[5];
    const float* gw   = (const float*)d_in[6];
    const float* gb   = (const float*)d_in[7];
    const float* lng  = (const float*)d_in[8];
    const float* lnb  = (const float*)d_in[9];
    const float* entw = (const float*)d_in[10];
    const float* entb = (const float*)d_in[11];
    const float* prw  = (const float*)d_in[12];
    const float* prb  = (const float*)d_in[13];
    const float* relw = (const float*)d_in[14];
    const float* relb = (const float*)d_in[15];
    float* out = (float*)d_out;
    char* base = (char*)d_ws;

    // ws layout (bytes)
    u16* ipw_bf  = (u16*)(base + 0);          // 3,538,944
    u16* opw_bf  = (u16*)(base + 3538944);    // 1,179,648  } contiguous pair ->
    u16* gw_bf   = (u16*)(base + 4718592);    // 1,179,648  } combined [1536][768]
    u16* entw_bf = (u16*)(base + 5898240);    // 1,769,472
    u16* relw_bf = (u16*)(base + 7667712);    // 4,718,592
    u16* hs_bf   = (u16*)(base + 12386304);   // 6,291,456
    u16* qkv_bf  = (u16*)(base + 18677760);   // 18,874,368 [dead after attn]
    u16* vt_bf   = (u16*)(base + 37552128);   // 6,291,456  [dead after attn]
    u16* ctx_bf  = (u16*)(base + 77398016);   // 6,291,456
    u16* aogl_bf = (u16*)(base + 83689472);   // 12,582,912
    float* bias2 = (float*)(base + 96272384); //      6,144 (opb|gb)
    float* pmax  = (float*)(base + 97329152); //  2,359,296
    u16* relh_bf = (u16*)(base + 43843584);   // 12,582,912
    u16* projr   = (u16*)(base + 56426496);   // 12,582,912
    float* enh   = out + OUT_ENH_OFF;

    const float qscale = 0.07216878364870323f; // 1/sqrt(192)

    // 0. casts (+ bias2 concat in blocks 9120/9121)
    cast_all<<<9122, 256, 0, stream>>>(hs, ipw, opw, gw, entw, relw, opb, gb,
                                       hs_bf, ipw_bf, opw_bf, gw_bf, entw_bf, relw_bf,
                                       bias2);

    // 1. qkv = hs @ in_proj_w.T + b (4096 x 2304, K=768) + fused V-transpose
    gemm_mfma<128,96,7,1,0><<<dim3(24, 32, 1), 256, 0, stream>>>(
        hs_bf, ipw_bf, ipb, qkv_bf, H_, H_, H_, H3_, 1,
        0,0,0,0,0,0, nullptr, 0.0f, (float*)vt_bf);

    // 2. fused attention: ctx = softmax(QK^T) @ V   (512 blocks, XCD-pinned z)
    attn_fused<<<dim3(32, 16), 256, 0, stream>>>(
        qkv_bf, vt_bf, mask, ctx_bf, qscale);

    // 3. [attn_out | gate_lin] = ctx @ [opw|gw]^T + [opb|gb]  (4096 x 1536, K=768)
    gemm_mfma<128,96,0,1,1><<<dim3(16, 32, 1), 256, 0, stream>>>(
        ctx_bf, opw_bf, bias2, aogl_bf, H_, H_, H_, 2 * H_, 1,
        0,0,0,0,0,0, nullptr, 0.0f, nullptr);

    // 4. enhanced = LN(hs + sigmoid(gl)*ao) -> enh fp32 + relh[:768]
    gate_ln_bf<<<MBS_, 256, 0, stream>>>(hs, aogl_bf, lng, lnb, enh, relh_bf);

    // 5. ent projection + fused RoPE (4096 x 1152, K=768) -> projr bf16
    gemm_mfma<64,96,4,1,1><<<dim3(12, 64, 1), 256, 0, stream>>>(
        relh_bf, entw_bf, entb, projr, H_, 2 * H_, H_, E_ * 2 * D_, 1,
        0,0,0,0,0,0, nullptr, 0.0f, nullptr);

    // 6. ent logits + fused rowmax partials -> out[0], pmax   (K=64)
    gemm_mfma<128,128,3,0,0><<<dim3(8, 8, B_ * E_), 256, 0, stream>>>(
        projr, projr + D_, nullptr, out, D_, E_ * 2 * D_, E_ * 2 * D_, S_, E_,
        (long)S_ * E_ * 2 * D_, 2 * D_, (long)S_ * E_ * 2 * D_, 2 * D_,
        (long)E_ * S_ * S_, (long)S_ * S_, mask, 0.0f, pmax);

    // 7. prior reduce + feat -> relh[:, 768:]
    prior_fused<<<MBS_, 256, 0, stream>>>(pmax, prw, prb, relh_bf);

    // 8. rel projection + fused RoPE (4096 x 1536, K=1536) -> projr bf16
    gemm_mfma<128,96,4,1,1><<<dim3(16, 32, 1), 256, 0, stream>>>(
        relh_bf, relw_bf, relb, projr, 2 * H_, 2 * H_, 2 * H_, R_ * 2 * D_, 1,
        0,0,0,0,0,0, nullptr, 0.0f, nullptr);

    // 9. rel logits -> out[1]   (48 x 1024 x 1024, K=64)
    gemm_mfma<128,128,1,0,0><<<dim3(8, 8, B_ * R_), 256, 0, stream>>>(
        projr, projr + D_, nullptr, out + OUT_REL_OFF, D_, R_ * 2 * D_, R_ * 2 * D_, S_, R_,
        (long)S_ * R_ * 2 * D_, 2 * D_, (long)S_ * R_ * 2 * D_, 2 * D_,
        (long)R_ * S_ * S_, (long)S_ * S_, mask, 0.0f, nullptr);

    (void)in_sizes; (void)n_in; (void)out_size; (void)ws_size;
}